// Round 7
// baseline (431.546 us; speedup 1.0000x reference)
//
#include <hip/hip_runtime.h>
#include <hip/hip_bf16.h>

#define N_NODES 50000
#define N_EDGES 1600000
#define N_CAND  1000
#define N_GRAPHS 50
#define EMB 32
#define L_LAYERS 4

#define BSH 8
#define BNODES 256
#define NBK ((N_NODES + BNODES - 1) >> BSH)    // 196 buckets of 256 nodes
#define STILE 2048
#define NBLK_S ((N_EDGES + STILE - 1) / STILE) // 782

#define W1A_OFF 0
#define W1B_OFF 4096
#define W2_OFF  8192
#define WE_OFF  12288
#define C1_OFF  12416
#define C2_OFF  12544
#define H_OFF   12800
#define NODE_F  (N_NODES * EMB)

#define BH_OFF    (H_OFF + 4 * NODE_F)                   // int[NBK]
#define BOFF_OFF  (BH_OFF + NBK)                         // int[NBK+1]
#define BCUR_OFF  (BOFF_OFF + NBK + 1)                   // int[NBK]
#define OFFS_OFF  (BCUR_OFF + NBK)                       // int[N_NODES+1]
#define CSR_OFF   (((OFFS_OFF + N_NODES + 1) + 1) & ~1)  // int2[N_EDGES] node-ordered
// stage (int2[N_EDGES] = 12.8MB) aliases hA/hB region (used before node_k runs)

typedef float f32x4 __attribute__((ext_vector_type(4)));
typedef __bf16 bf16x8 __attribute__((ext_vector_type(8)));
union BF8 { __bf16 b[8]; bf16x8 v; };

__global__ void prep_k(const float* __restrict__ W1, const float* __restrict__ b1,
                       const float* __restrict__ g1, const float* __restrict__ be1,
                       const float* __restrict__ m1, const float* __restrict__ v1,
                       const float* __restrict__ W2, const float* __restrict__ b2,
                       const float* __restrict__ g2, const float* __restrict__ be2,
                       const float* __restrict__ m2, const float* __restrict__ v2,
                       float* __restrict__ ws) {
    int t = threadIdx.x;  // 256 threads, 1 block
    for (int l = 0; l < L_LAYERS; ++l) {
        for (int i = t; i < 1024; i += 256) {
            int k = i >> 5, j = i & 31;
            float s1 = g1[l * 32 + j] * rsqrtf(v1[l * 32 + j] + 1e-5f);
            float s2 = g2[l * 32 + j] * rsqrtf(v2[l * 32 + j] + 1e-5f);
            ws[W1A_OFF + l * 1024 + i] = W1[(l * 65 + k) * 32 + j] * s1;
            ws[W1B_OFF + l * 1024 + i] = W1[(l * 65 + 32 + k) * 32 + j] * s1;
            ws[W2_OFF  + l * 1024 + i] = W2[(l * 32 + k) * 32 + j] * s2;
            if (k == 0) {
                ws[WE_OFF + l * 32 + j] = W1[(l * 65 + 64) * 32 + j] * s1;
                ws[C1_OFF + l * 32 + j] = b1[l * 32 + j] * s1 + be1[l * 32 + j] - m1[l * 32 + j] * s1;
                ws[C2_OFF + l * 32 + j] = b2[l * 32 + j] * s2 + be2[l * 32 + j] - m2[l * 32 + j] * s2;
            }
        }
    }
}

__global__ void embed_k(const float* __restrict__ x, const float* __restrict__ Win,
                        const float* __restrict__ bin, float* __restrict__ h) {
    int t = blockIdx.x * blockDim.x + threadIdx.x;
    if (t >= NODE_F) return;
    int n = t >> 5, j = t & 31;
    h[t] = x[2 * n] * Win[j] + x[2 * n + 1] * Win[32 + j] + bin[j];
}

__global__ void zero_k(int* __restrict__ p, int n) {
    int t = blockIdx.x * blockDim.x + threadIdx.x;
    if (t < n) p[t] = 0;
}

// per-block LDS histogram of dst>>BSH, one global atomic per bucket per block
__global__ void bhist_k(const int* __restrict__ ei, int* __restrict__ bh) {
    __shared__ int lh[NBK];
    for (int i = threadIdx.x; i < NBK; i += 256) lh[i] = 0;
    __syncthreads();
    int tb = blockIdx.x * STILE;
#pragma unroll
    for (int i = 0; i < STILE / 256; ++i) {
        int e = tb + i * 256 + threadIdx.x;
        if (e < N_EDGES) atomicAdd(&lh[ei[N_EDGES + e] >> BSH], 1);
    }
    __syncthreads();
    for (int i = threadIdx.x; i < NBK; i += 256)
        if (lh[i]) atomicAdd(&bh[i], lh[i]);
}

// single block: exclusive scan of bh[NBK] -> boffs, bcur
__global__ void bscan_k(const int* __restrict__ bh, int* __restrict__ boffs,
                        int* __restrict__ bcur) {
    __shared__ int part[1024];
    const int CH = (NBK + 1023) / 1024;  // 1
    int t = threadIdx.x;
    int base = t * CH;
    int s = 0;
    for (int i = 0; i < CH; ++i) {
        int idx = base + i;
        if (idx < NBK) s += bh[idx];
    }
    part[t] = s;
    __syncthreads();
    for (int d = 1; d < 1024; d <<= 1) {
        int v = (t >= d) ? part[t - d] : 0;
        __syncthreads();
        part[t] += v;
        __syncthreads();
    }
    int run = part[t] - s;
    for (int i = 0; i < CH; ++i) {
        int idx = base + i;
        if (idx < NBK) {
            boffs[idx] = run;
            bcur[idx] = run;
            run += bh[idx];
        }
    }
    if (t == 1023) boffs[NBK] = N_EDGES;
}

// block-aggregated binning: LDS hist -> one global reserve per bucket -> direct write
__global__ void bscatter_k(const int* __restrict__ ei, const float* __restrict__ ea,
                           int* __restrict__ bcur, int2* __restrict__ stage) {
    __shared__ int lofs[NBK];
    for (int i = threadIdx.x; i < NBK; i += 256) lofs[i] = 0;
    __syncthreads();
    int tb = blockIdx.x * STILE;
#pragma unroll
    for (int i = 0; i < STILE / 256; ++i) {
        int e = tb + i * 256 + threadIdx.x;
        if (e < N_EDGES) atomicAdd(&lofs[ei[N_EDGES + e] >> BSH], 1);
    }
    __syncthreads();
    for (int bk = threadIdx.x; bk < NBK; bk += 256) {
        int c = lofs[bk];
        lofs[bk] = c ? atomicAdd(&bcur[bk], c) : 0;
    }
    __syncthreads();
#pragma unroll
    for (int i = 0; i < STILE / 256; ++i) {
        int e = tb + i * 256 + threadIdx.x;
        if (e < N_EDGES) {
            int src = ei[e], dst = ei[N_EDGES + e];
            int bk = dst >> BSH;
            int pos = atomicAdd(&lofs[bk], 1);
            int2 p;
            p.x = src | ((dst & (BNODES - 1)) << 16);
            p.y = __float_as_int(ea[e]);
            stage[pos] = p;
        }
    }
}

// one block per 256-node bucket: hist + wave-scan prefix -> offs[n]; exact scatter.
// All writes land in the bucket's own contiguous window (L2-resident).
__global__ void bsort2_k(const int* __restrict__ boffs, const int2* __restrict__ stage,
                         int* __restrict__ offs, int2* __restrict__ csr) {
    __shared__ int cnt[BNODES];
    __shared__ int pre[BNODES];
    __shared__ int cur[BNODES];
    const int b = blockIdx.x;
    const int nbase = b << BSH;
    const int t = threadIdx.x;
    const int beg = boffs[b], end = boffs[b + 1];
    cnt[t] = 0;
    __syncthreads();
    for (int i = beg + t; i < end; i += 256)
        atomicAdd(&cnt[(stage[i].x >> 16) & (BNODES - 1)], 1);
    __syncthreads();
    if (t < 64) {
        int b4 = t * 4;
        int c0 = cnt[b4], c1 = cnt[b4 + 1], c2 = cnt[b4 + 2], c3 = cnt[b4 + 3];
        int s = c0 + c1 + c2 + c3;
        int run = s;
#pragma unroll
        for (int d = 1; d < 64; d <<= 1) {
            int v = __shfl_up(run, d, 64);
            if (t >= d) run += v;
        }
        int ex = run - s;  // exclusive
        pre[b4] = ex; pre[b4 + 1] = ex + c0; pre[b4 + 2] = ex + c0 + c1; pre[b4 + 3] = ex + c0 + c1 + c2;
    }
    __syncthreads();
    cur[t] = pre[t];
    {
        int n = nbase + t;
        if (n < N_NODES) offs[n] = beg + pre[t];
    }
    if (b == NBK - 1 && t == 0) offs[N_NODES] = N_EDGES;
    __syncthreads();
    for (int i = beg + t; i < end; i += 256) {
        int2 p = stage[i];
        int dloc = (p.x >> 16) & (BNODES - 1);
        int pos = beg + atomicAdd(&cur[dloc], 1);
        int2 q; q.x = p.x & 0xFFFF; q.y = p.y;
        csr[pos] = q;
    }
}

// ---------------- per-layer kernels ----------------
__global__ void node_k(const float* __restrict__ h, const float* __restrict__ ws, int l,
                       float* __restrict__ hA, float* __restrict__ hB) {
    __shared__ float sA[1024], sB[1024];
    const float* W1A = ws + W1A_OFF + l * 1024;
    const float* W1B = ws + W1B_OFF + l * 1024;
    for (int i = threadIdx.x; i < 1024; i += blockDim.x) { sA[i] = W1A[i]; sB[i] = W1B[i]; }
    __syncthreads();
    int t = blockIdx.x * blockDim.x + threadIdx.x;
    if (t >= NODE_F) return;
    int j = t & 31;
    float hv = h[t];
    float a = ws[C1_OFF + l * 32 + j];
    float b = 0.f;
#pragma unroll
    for (int k = 0; k < 32; ++k) {
        float hk = __shfl(hv, k, 32);
        a += hk * sA[k * 32 + j];
        b += hk * sB[k * 32 + j];
    }
    hA[t] = a;
    hB[t] = b;
}

// One wave per node; 32 edges per iteration (2 A-frags, 4 MFMAs).
// A frag: lane l = row l&15, k = 8*(l>>4)+i. C/D: col=lane&15, row=4*(lane>>4)+reg.
// C2 folded into MFMA C-operand; tail predication as 0/1 float * fmaf.
__launch_bounds__(256)
__global__ void edge_mfma_k(const int* __restrict__ offs, const int2* __restrict__ csr,
                            const float* __restrict__ ws, int l,
                            const float* __restrict__ h, const float* __restrict__ hA,
                            const float* __restrict__ hB, float* __restrict__ hnext) {
    const int lane = threadIdx.x & 63;
    const int n = blockIdx.x * 4 + (threadIdx.x >> 6);
    if (n >= N_NODES) return;
    const int r = lane & 15;   // A row (edge slot) / D col (channel)
    const int q = lane >> 4;   // channel octet / D row quad

    const float* W2p = ws + W2_OFF + l * 1024;
    BF8 b0, b1;
#pragma unroll
    for (int i = 0; i < 8; ++i) {
        b0.b[i] = (__bf16)W2p[(8 * q + i) * 32 + r];
        b1.b[i] = (__bf16)W2p[(8 * q + i) * 32 + 16 + r];
    }
    const float c2a = ws[C2_OFF + l * 32 + r];
    const float c2b = ws[C2_OFF + l * 32 + 16 + r];
    const f32x4 zc0 = {c2a, c2a, c2a, c2a};
    const f32x4 zc1 = {c2b, c2b, c2b, c2b};
    const f32x4 hA0 = *(const f32x4*)(hA + n * 32 + 8 * q);
    const f32x4 hA1 = *(const f32x4*)(hA + n * 32 + 8 * q + 4);
    const f32x4 we0 = *(const f32x4*)(ws + WE_OFF + l * 32 + 8 * q);
    const f32x4 we1 = *(const f32x4*)(ws + WE_OFF + l * 32 + 8 * q + 4);

    const int beg = offs[n], end = offs[n + 1];
    float ns0 = 0.f, ns1 = 0.f;

    for (int ebase = beg; ebase < end; ebase += 32) {
        const int last = end - 1;
        int e0 = ebase + r;       e0 = (e0 < last) ? e0 : last;
        int e1 = ebase + 16 + r;  e1 = (e1 < last) ? e1 : last;
        int2 p0 = csr[e0];
        int2 p1 = csr[e1];
        int s0 = p0.x; float ea0 = __int_as_float(p0.y);
        int s1 = p1.x; float ea1 = __int_as_float(p1.y);
        const f32x4 hb00 = *(const f32x4*)(hB + s0 * 32 + 8 * q);
        const f32x4 hb01 = *(const f32x4*)(hB + s0 * 32 + 8 * q + 4);
        const f32x4 hb10 = *(const f32x4*)(hB + s1 * 32 + 8 * q);
        const f32x4 hb11 = *(const f32x4*)(hB + s1 * 32 + 8 * q + 4);
        BF8 a0, a1;
#pragma unroll
        for (int i = 0; i < 4; ++i) {
            a0.b[i]     = (__bf16)fmaxf(hA0[i] + hb00[i] + ea0 * we0[i], 0.f);
            a0.b[i + 4] = (__bf16)fmaxf(hA1[i] + hb01[i] + ea0 * we1[i], 0.f);
            a1.b[i]     = (__bf16)fmaxf(hA0[i] + hb10[i] + ea1 * we0[i], 0.f);
            a1.b[i + 4] = (__bf16)fmaxf(hA1[i] + hb11[i] + ea1 * we1[i], 0.f);
        }
        f32x4 acc00 = __builtin_amdgcn_mfma_f32_16x16x32_bf16(a0.v, b0.v, zc0, 0, 0, 0);
        f32x4 acc01 = __builtin_amdgcn_mfma_f32_16x16x32_bf16(a0.v, b1.v, zc1, 0, 0, 0);
        f32x4 acc10 = __builtin_amdgcn_mfma_f32_16x16x32_bf16(a1.v, b0.v, zc0, 0, 0, 0);
        f32x4 acc11 = __builtin_amdgcn_mfma_f32_16x16x32_bf16(a1.v, b1.v, zc1, 0, 0, 0);
        int nreal = end - ebase;
#pragma unroll
        for (int reg = 0; reg < 4; ++reg) {
            int row = 4 * q + reg;
            float m0 = (row < nreal) ? 1.f : 0.f;
            float m1 = (row + 16 < nreal) ? 1.f : 0.f;
            ns0 = fmaf(m0, fmaxf(acc00[reg], 0.f), ns0);
            ns1 = fmaf(m0, fmaxf(acc01[reg], 0.f), ns1);
            ns0 = fmaf(m1, fmaxf(acc10[reg], 0.f), ns0);
            ns1 = fmaf(m1, fmaxf(acc11[reg], 0.f), ns1);
        }
    }
    ns0 += __shfl_xor(ns0, 16, 64);
    ns0 += __shfl_xor(ns0, 32, 64);
    ns1 += __shfl_xor(ns1, 16, 64);
    ns1 += __shfl_xor(ns1, 32, 64);
    if (lane < 32) {
        float base = h[n * 32 + lane];
        hnext[n * 32 + lane] = base + ((lane & 16) ? ns1 : ns0);
    }
}

__global__ void head_k(const float* __restrict__ h, const int* __restrict__ cand,
                       const int* __restrict__ batch, const float* __restrict__ Wout,
                       const float* __restrict__ bout, float* __restrict__ out) {
    __shared__ float Lg[N_CAND];
    __shared__ int Sg[N_CAND];
    __shared__ float gm[N_GRAPHS], gs[N_GRAPHS];
    int t = threadIdx.x;  // 1024
    if (t < N_CAND) {
        int c = cand[t];
        float acc = bout[0];
#pragma unroll
        for (int j = 0; j < 32; ++j) acc += h[c * 32 + j] * Wout[j];
        Lg[t] = acc;
        Sg[t] = batch[c];
    }
    __syncthreads();
    if (t < 16 * N_GRAPHS) {
        int g = t >> 4, s = t & 15;
        float m = -1e30f;
        for (int i = s; i < N_CAND; i += 16)
            if (Sg[i] == g) m = fmaxf(m, Lg[i]);
#pragma unroll
        for (int d = 1; d < 16; d <<= 1) m = fmaxf(m, __shfl_xor(m, d, 64));
        float ssum = 0.f;
        for (int i = s; i < N_CAND; i += 16)
            if (Sg[i] == g) ssum += expf(Lg[i] - m);
#pragma unroll
        for (int d = 1; d < 16; d <<= 1) ssum += __shfl_xor(ssum, d, 64);
        if (s == 0) { gm[g] = m; gs[g] = logf(ssum); }
    }
    __syncthreads();
    if (t < N_CAND) out[t] = Lg[t] - gm[Sg[t]] - gs[Sg[t]];
}

extern "C" void kernel_launch(void* const* d_in, const int* in_sizes, int n_in,
                              void* d_out, int out_size, void* d_ws, size_t ws_size,
                              hipStream_t stream) {
    const float* x    = (const float*)d_in[0];
    const int*   ei   = (const int*)d_in[1];
    const float* eatt = (const float*)d_in[2];
    const int*   cand = (const int*)d_in[3];
    const int*   batch= (const int*)d_in[4];
    const float* Win  = (const float*)d_in[5];
    const float* bin  = (const float*)d_in[6];
    const float* W1   = (const float*)d_in[7];
    const float* b1   = (const float*)d_in[8];
    const float* g1   = (const float*)d_in[9];
    const float* be1  = (const float*)d_in[10];
    const float* m1   = (const float*)d_in[11];
    const float* v1   = (const float*)d_in[12];
    const float* W2   = (const float*)d_in[13];
    const float* b2   = (const float*)d_in[14];
    const float* g2   = (const float*)d_in[15];
    const float* be2  = (const float*)d_in[16];
    const float* m2   = (const float*)d_in[17];
    const float* v2   = (const float*)d_in[18];
    const float* Wout = (const float*)d_in[19];
    const float* bout = (const float*)d_in[20];
    float* out = (float*)d_out;
    float* ws = (float*)d_ws;

    float* h0 = ws + H_OFF;
    float* h1 = ws + H_OFF + NODE_F;
    float* hA = ws + H_OFF + 2 * NODE_F;
    float* hB = ws + H_OFF + 3 * NODE_F;
    int* bh    = (int*)(ws + BH_OFF);
    int* boffs = (int*)(ws + BOFF_OFF);
    int* bcur  = (int*)(ws + BCUR_OFF);
    int* offs  = (int*)(ws + OFFS_OFF);
    int2* csr  = (int2*)(ws + CSR_OFF);
    int2* stage = (int2*)(ws + H_OFF + 2 * NODE_F);  // aliases hA/hB (pre-node_k only)

    prep_k<<<1, 256, 0, stream>>>(W1, b1, g1, be1, m1, v1, W2, b2, g2, be2, m2, v2, ws);
    embed_k<<<(NODE_F + 255) / 256, 256, 0, stream>>>(x, Win, bin, h0);

    zero_k<<<(NBK + 255) / 256, 256, 0, stream>>>(bh, NBK);
    bhist_k<<<NBLK_S, 256, 0, stream>>>(ei, bh);
    bscan_k<<<1, 1024, 0, stream>>>(bh, boffs, bcur);
    bscatter_k<<<NBLK_S, 256, 0, stream>>>(ei, eatt, bcur, stage);
    bsort2_k<<<NBK, 256, 0, stream>>>(boffs, stage, offs, csr);

    float* cur = h0;
    float* nxt = h1;
    for (int l = 0; l < L_LAYERS; ++l) {
        node_k<<<(NODE_F + 1023) / 1024, 1024, 0, stream>>>(cur, ws, l, hA, hB);
        edge_mfma_k<<<(N_NODES + 3) / 4, 256, 0, stream>>>(offs, csr, ws, l,
                                                           cur, hA, hB, nxt);
        float* tmp = cur; cur = nxt; nxt = tmp;
    }

    head_k<<<1, 1024, 0, stream>>>(cur, cand, batch, Wout, bout, out);
}

// Round 8
// 387.506 us; speedup vs baseline: 1.1137x; 1.1137x over previous
//
#include <hip/hip_runtime.h>
#include <hip/hip_bf16.h>

#define N_NODES 50000
#define N_EDGES 1600000
#define N_CAND  1000
#define N_GRAPHS 50
#define EMB 32
#define L_LAYERS 4

#define BSH 8
#define BNODES 256
#define NBK ((N_NODES + BNODES - 1) >> BSH)    // 196 buckets of 256 nodes
#define STILE 2048
#define NBLK_S ((N_EDGES + STILE - 1) / STILE) // 782

#define NPW 4  // nodes per wave in edge kernel

#define W1A_OFF 0
#define W1B_OFF 4096
#define W2_OFF  8192
#define WE_OFF  12288
#define C1_OFF  12416
#define C2_OFF  12544
#define H_OFF   12800
#define NODE_F  (N_NODES * EMB)

#define BH_OFF    (H_OFF + 4 * NODE_F)                   // int[NBK]
#define BOFF_OFF  (BH_OFF + NBK)                         // int[NBK+1]
#define BCUR_OFF  (BOFF_OFF + NBK + 1)                   // int[NBK]
#define OFFS_OFF  (BCUR_OFF + NBK)                       // int[N_NODES+1]
#define CSR_OFF   (((OFFS_OFF + N_NODES + 1) + 1) & ~1)  // int2[N_EDGES] node-ordered
// stage (int2[N_EDGES] = 12.8MB) aliases hA/hB region (used before node_k runs)

typedef float f32x4 __attribute__((ext_vector_type(4)));
typedef __bf16 bf16x8 __attribute__((ext_vector_type(8)));
union BF8 { __bf16 b[8]; bf16x8 v; };

__global__ void prep_k(const float* __restrict__ W1, const float* __restrict__ b1,
                       const float* __restrict__ g1, const float* __restrict__ be1,
                       const float* __restrict__ m1, const float* __restrict__ v1,
                       const float* __restrict__ W2, const float* __restrict__ b2,
                       const float* __restrict__ g2, const float* __restrict__ be2,
                       const float* __restrict__ m2, const float* __restrict__ v2,
                       float* __restrict__ ws) {
    int t = threadIdx.x;  // 256 threads, 1 block
    for (int l = 0; l < L_LAYERS; ++l) {
        for (int i = t; i < 1024; i += 256) {
            int k = i >> 5, j = i & 31;
            float s1 = g1[l * 32 + j] * rsqrtf(v1[l * 32 + j] + 1e-5f);
            float s2 = g2[l * 32 + j] * rsqrtf(v2[l * 32 + j] + 1e-5f);
            ws[W1A_OFF + l * 1024 + i] = W1[(l * 65 + k) * 32 + j] * s1;
            ws[W1B_OFF + l * 1024 + i] = W1[(l * 65 + 32 + k) * 32 + j] * s1;
            ws[W2_OFF  + l * 1024 + i] = W2[(l * 32 + k) * 32 + j] * s2;
            if (k == 0) {
                ws[WE_OFF + l * 32 + j] = W1[(l * 65 + 64) * 32 + j] * s1;
                ws[C1_OFF + l * 32 + j] = b1[l * 32 + j] * s1 + be1[l * 32 + j] - m1[l * 32 + j] * s1;
                ws[C2_OFF + l * 32 + j] = b2[l * 32 + j] * s2 + be2[l * 32 + j] - m2[l * 32 + j] * s2;
            }
        }
    }
}

__global__ void embed_k(const float* __restrict__ x, const float* __restrict__ Win,
                        const float* __restrict__ bin, float* __restrict__ h) {
    int t = blockIdx.x * blockDim.x + threadIdx.x;
    if (t >= NODE_F) return;
    int n = t >> 5, j = t & 31;
    h[t] = x[2 * n] * Win[j] + x[2 * n + 1] * Win[32 + j] + bin[j];
}

__global__ void zero_k(int* __restrict__ p, int n) {
    int t = blockIdx.x * blockDim.x + threadIdx.x;
    if (t < n) p[t] = 0;
}

// per-block LDS histogram of dst>>BSH, one global atomic per bucket per block
__global__ void bhist_k(const int* __restrict__ ei, int* __restrict__ bh) {
    __shared__ int lh[NBK];
    for (int i = threadIdx.x; i < NBK; i += 256) lh[i] = 0;
    __syncthreads();
    int tb = blockIdx.x * STILE;
#pragma unroll
    for (int i = 0; i < STILE / 256; ++i) {
        int e = tb + i * 256 + threadIdx.x;
        if (e < N_EDGES) atomicAdd(&lh[ei[N_EDGES + e] >> BSH], 1);
    }
    __syncthreads();
    for (int i = threadIdx.x; i < NBK; i += 256)
        if (lh[i]) atomicAdd(&bh[i], lh[i]);
}

// single block: exclusive scan of bh[NBK] -> boffs, bcur
__global__ void bscan_k(const int* __restrict__ bh, int* __restrict__ boffs,
                        int* __restrict__ bcur) {
    __shared__ int part[1024];
    const int CH = (NBK + 1023) / 1024;  // 1
    int t = threadIdx.x;
    int base = t * CH;
    int s = 0;
    for (int i = 0; i < CH; ++i) {
        int idx = base + i;
        if (idx < NBK) s += bh[idx];
    }
    part[t] = s;
    __syncthreads();
    for (int d = 1; d < 1024; d <<= 1) {
        int v = (t >= d) ? part[t - d] : 0;
        __syncthreads();
        part[t] += v;
        __syncthreads();
    }
    int run = part[t] - s;
    for (int i = 0; i < CH; ++i) {
        int idx = base + i;
        if (idx < NBK) {
            boffs[idx] = run;
            bcur[idx] = run;
            run += bh[idx];
        }
    }
    if (t == 1023) boffs[NBK] = N_EDGES;
}

// block-aggregated binning: LDS hist -> one global reserve per bucket -> direct write
__global__ void bscatter_k(const int* __restrict__ ei, const float* __restrict__ ea,
                           int* __restrict__ bcur, int2* __restrict__ stage) {
    __shared__ int lofs[NBK];
    for (int i = threadIdx.x; i < NBK; i += 256) lofs[i] = 0;
    __syncthreads();
    int tb = blockIdx.x * STILE;
#pragma unroll
    for (int i = 0; i < STILE / 256; ++i) {
        int e = tb + i * 256 + threadIdx.x;
        if (e < N_EDGES) atomicAdd(&lofs[ei[N_EDGES + e] >> BSH], 1);
    }
    __syncthreads();
    for (int bk = threadIdx.x; bk < NBK; bk += 256) {
        int c = lofs[bk];
        lofs[bk] = c ? atomicAdd(&bcur[bk], c) : 0;
    }
    __syncthreads();
#pragma unroll
    for (int i = 0; i < STILE / 256; ++i) {
        int e = tb + i * 256 + threadIdx.x;
        if (e < N_EDGES) {
            int src = ei[e], dst = ei[N_EDGES + e];
            int bk = dst >> BSH;
            int pos = atomicAdd(&lofs[bk], 1);
            int2 p;
            p.x = src | ((dst & (BNODES - 1)) << 16);
            p.y = __float_as_int(ea[e]);
            stage[pos] = p;
        }
    }
}

// one block per 256-node bucket: hist + wave-scan prefix -> offs[n]; exact scatter.
__global__ void bsort2_k(const int* __restrict__ boffs, const int2* __restrict__ stage,
                         int* __restrict__ offs, int2* __restrict__ csr) {
    __shared__ int cnt[BNODES];
    __shared__ int pre[BNODES];
    __shared__ int cur[BNODES];
    const int b = blockIdx.x;
    const int nbase = b << BSH;
    const int t = threadIdx.x;
    const int beg = boffs[b], end = boffs[b + 1];
    cnt[t] = 0;
    __syncthreads();
    for (int i = beg + t; i < end; i += 256)
        atomicAdd(&cnt[(stage[i].x >> 16) & (BNODES - 1)], 1);
    __syncthreads();
    if (t < 64) {
        int b4 = t * 4;
        int c0 = cnt[b4], c1 = cnt[b4 + 1], c2 = cnt[b4 + 2], c3 = cnt[b4 + 3];
        int s = c0 + c1 + c2 + c3;
        int run = s;
#pragma unroll
        for (int d = 1; d < 64; d <<= 1) {
            int v = __shfl_up(run, d, 64);
            if (t >= d) run += v;
        }
        int ex = run - s;  // exclusive
        pre[b4] = ex; pre[b4 + 1] = ex + c0; pre[b4 + 2] = ex + c0 + c1; pre[b4 + 3] = ex + c0 + c1 + c2;
    }
    __syncthreads();
    cur[t] = pre[t];
    {
        int n = nbase + t;
        if (n < N_NODES) offs[n] = beg + pre[t];
    }
    if (b == NBK - 1 && t == 0) offs[N_NODES] = N_EDGES;
    __syncthreads();
    for (int i = beg + t; i < end; i += 256) {
        int2 p = stage[i];
        int dloc = (p.x >> 16) & (BNODES - 1);
        int pos = beg + atomicAdd(&cur[dloc], 1);
        int2 q; q.x = p.x & 0xFFFF; q.y = p.y;
        csr[pos] = q;
    }
}

// ---------------- per-layer kernels ----------------
__global__ void node_k(const float* __restrict__ h, const float* __restrict__ ws, int l,
                       float* __restrict__ hA, float* __restrict__ hB) {
    __shared__ float sA[1024], sB[1024];
    const float* W1A = ws + W1A_OFF + l * 1024;
    const float* W1B = ws + W1B_OFF + l * 1024;
    for (int i = threadIdx.x; i < 1024; i += blockDim.x) { sA[i] = W1A[i]; sB[i] = W1B[i]; }
    __syncthreads();
    int t = blockIdx.x * blockDim.x + threadIdx.x;
    if (t >= NODE_F) return;
    int j = t & 31;
    float hv = h[t];
    float a = ws[C1_OFF + l * 32 + j];
    float b = 0.f;
#pragma unroll
    for (int k = 0; k < 32; ++k) {
        float hk = __shfl(hv, k, 32);
        a += hk * sA[k * 32 + j];
        b += hk * sB[k * 32 + j];
    }
    hA[t] = a;
    hB[t] = b;
}

// One wave handles NPW nodes (pairs): frag0 = 16 edges of n0, frag1 = 16 edges of n1.
// A frag: lane l = row l&15, k = 8*(l>>4)+i. C/D: col=lane&15, row=4*(lane>>4)+reg.
// C2 folded into MFMA C-operand; tail predication as 0/1 float * fmaf.
__launch_bounds__(256)
__global__ void edge_mfma_k(const int* __restrict__ offs, const int2* __restrict__ csr,
                            const float* __restrict__ ws, int l,
                            const float* __restrict__ h, const float* __restrict__ hA,
                            const float* __restrict__ hB, float* __restrict__ hnext) {
    const int lane = threadIdx.x & 63;
    const int wid = (blockIdx.x * 256 + threadIdx.x) >> 6;
    const int r = lane & 15;   // A row (edge slot) / D col (channel)
    const int q = lane >> 4;   // channel octet / D row quad

    const float* W2p = ws + W2_OFF + l * 1024;
    BF8 b0, b1;
#pragma unroll
    for (int i = 0; i < 8; ++i) {
        b0.b[i] = (__bf16)W2p[(8 * q + i) * 32 + r];
        b1.b[i] = (__bf16)W2p[(8 * q + i) * 32 + 16 + r];
    }
    const float c2a = ws[C2_OFF + l * 32 + r];
    const float c2b = ws[C2_OFF + l * 32 + 16 + r];
    const f32x4 zc0 = {c2a, c2a, c2a, c2a};
    const f32x4 zc1 = {c2b, c2b, c2b, c2b};
    const f32x4 we0 = *(const f32x4*)(ws + WE_OFF + l * 32 + 8 * q);
    const f32x4 we1 = *(const f32x4*)(ws + WE_OFF + l * 32 + 8 * q + 4);

    const int nbase = wid * NPW;
#pragma unroll
    for (int ni = 0; ni < NPW; ni += 2) {
        const int n0 = nbase + ni;
        if (n0 >= N_NODES) return;
        const int n1 = n0 + 1;
        const bool has1 = (n1 < N_NODES);
        const int o0 = offs[n0];
        const int o1 = offs[n0 + 1];
        const int o2 = has1 ? offs[n1 + 1] : o1;

        const f32x4 hA00 = *(const f32x4*)(hA + n0 * 32 + 8 * q);
        const f32x4 hA01 = *(const f32x4*)(hA + n0 * 32 + 8 * q + 4);
        const f32x4 hA10 = has1 ? *(const f32x4*)(hA + n1 * 32 + 8 * q) : zc0;
        const f32x4 hA11 = has1 ? *(const f32x4*)(hA + n1 * 32 + 8 * q + 4) : zc0;

        float ns00 = 0.f, ns01 = 0.f, ns10 = 0.f, ns11 = 0.f;
        const int d0 = o1 - o0, d1 = o2 - o1;
        int nit = (d0 + 15) >> 4;
        int nit1 = (d1 + 15) >> 4;
        if (nit1 > nit) nit = nit1;

        int eb0 = o0, eb1 = o1;
        for (int it = 0; it < nit; ++it, eb0 += 16, eb1 += 16) {
            int e0 = eb0 + r; e0 = (e0 < o1 - 1) ? e0 : (o1 - 1); e0 = (e0 > 0) ? e0 : 0;
            int e1 = eb1 + r; e1 = (e1 < o2 - 1) ? e1 : (o2 - 1); e1 = (e1 > 0) ? e1 : 0;
            int2 p0 = csr[e0];
            int2 p1 = csr[e1];
            int s0 = p0.x; float ea0 = __int_as_float(p0.y);
            int s1 = p1.x; float ea1 = __int_as_float(p1.y);
            const f32x4 hb00 = *(const f32x4*)(hB + s0 * 32 + 8 * q);
            const f32x4 hb01 = *(const f32x4*)(hB + s0 * 32 + 8 * q + 4);
            const f32x4 hb10 = *(const f32x4*)(hB + s1 * 32 + 8 * q);
            const f32x4 hb11 = *(const f32x4*)(hB + s1 * 32 + 8 * q + 4);
            BF8 a0, a1;
#pragma unroll
            for (int i = 0; i < 4; ++i) {
                a0.b[i]     = (__bf16)fmaxf(hA00[i] + hb00[i] + ea0 * we0[i], 0.f);
                a0.b[i + 4] = (__bf16)fmaxf(hA01[i] + hb01[i] + ea0 * we1[i], 0.f);
                a1.b[i]     = (__bf16)fmaxf(hA10[i] + hb10[i] + ea1 * we0[i], 0.f);
                a1.b[i + 4] = (__bf16)fmaxf(hA11[i] + hb11[i] + ea1 * we1[i], 0.f);
            }
            f32x4 acc00 = __builtin_amdgcn_mfma_f32_16x16x32_bf16(a0.v, b0.v, zc0, 0, 0, 0);
            f32x4 acc01 = __builtin_amdgcn_mfma_f32_16x16x32_bf16(a0.v, b1.v, zc1, 0, 0, 0);
            f32x4 acc10 = __builtin_amdgcn_mfma_f32_16x16x32_bf16(a1.v, b0.v, zc0, 0, 0, 0);
            f32x4 acc11 = __builtin_amdgcn_mfma_f32_16x16x32_bf16(a1.v, b1.v, zc1, 0, 0, 0);
            int nr0 = o1 - eb0;   // rows valid if row < nr0
            int nr1 = o2 - eb1;
#pragma unroll
            for (int reg = 0; reg < 4; ++reg) {
                int row = 4 * q + reg;
                float m0 = (row < nr0) ? 1.f : 0.f;
                float m1 = (row < nr1) ? 1.f : 0.f;
                ns00 = fmaf(m0, fmaxf(acc00[reg], 0.f), ns00);
                ns01 = fmaf(m0, fmaxf(acc01[reg], 0.f), ns01);
                ns10 = fmaf(m1, fmaxf(acc10[reg], 0.f), ns10);
                ns11 = fmaf(m1, fmaxf(acc11[reg], 0.f), ns11);
            }
        }
        // reduce over row-quads (q): lanes differing in bits 4,5
        ns00 += __shfl_xor(ns00, 16, 64);
        ns00 += __shfl_xor(ns00, 32, 64);
        ns01 += __shfl_xor(ns01, 16, 64);
        ns01 += __shfl_xor(ns01, 32, 64);
        ns10 += __shfl_xor(ns10, 16, 64);
        ns10 += __shfl_xor(ns10, 32, 64);
        ns11 += __shfl_xor(ns11, 16, 64);
        ns11 += __shfl_xor(ns11, 32, 64);
        // lanes 0..31 store node0, lanes 32..63 store node1
        int ll = lane & 31;
        if (lane < 32) {
            float base = h[n0 * 32 + ll];
            hnext[n0 * 32 + ll] = base + ((ll & 16) ? ns01 : ns00);
        } else if (has1) {
            float base = h[n1 * 32 + ll];
            hnext[n1 * 32 + ll] = base + ((ll & 16) ? ns11 : ns10);
        }
    }
}

__global__ void head_k(const float* __restrict__ h, const int* __restrict__ cand,
                       const int* __restrict__ batch, const float* __restrict__ Wout,
                       const float* __restrict__ bout, float* __restrict__ out) {
    __shared__ float Lg[N_CAND];
    __shared__ int Sg[N_CAND];
    __shared__ float gm[N_GRAPHS], gs[N_GRAPHS];
    int t = threadIdx.x;  // 1024
    if (t < N_CAND) {
        int c = cand[t];
        float acc = bout[0];
#pragma unroll
        for (int j = 0; j < 32; ++j) acc += h[c * 32 + j] * Wout[j];
        Lg[t] = acc;
        Sg[t] = batch[c];
    }
    __syncthreads();
    if (t < 16 * N_GRAPHS) {
        int g = t >> 4, s = t & 15;
        float m = -1e30f;
        for (int i = s; i < N_CAND; i += 16)
            if (Sg[i] == g) m = fmaxf(m, Lg[i]);
#pragma unroll
        for (int d = 1; d < 16; d <<= 1) m = fmaxf(m, __shfl_xor(m, d, 64));
        float ssum = 0.f;
        for (int i = s; i < N_CAND; i += 16)
            if (Sg[i] == g) ssum += expf(Lg[i] - m);
#pragma unroll
        for (int d = 1; d < 16; d <<= 1) ssum += __shfl_xor(ssum, d, 64);
        if (s == 0) { gm[g] = m; gs[g] = logf(ssum); }
    }
    __syncthreads();
    if (t < N_CAND) out[t] = Lg[t] - gm[Sg[t]] - gs[Sg[t]];
}

extern "C" void kernel_launch(void* const* d_in, const int* in_sizes, int n_in,
                              void* d_out, int out_size, void* d_ws, size_t ws_size,
                              hipStream_t stream) {
    const float* x    = (const float*)d_in[0];
    const int*   ei   = (const int*)d_in[1];
    const float* eatt = (const float*)d_in[2];
    const int*   cand = (const int*)d_in[3];
    const int*   batch= (const int*)d_in[4];
    const float* Win  = (const float*)d_in[5];
    const float* bin  = (const float*)d_in[6];
    const float* W1   = (const float*)d_in[7];
    const float* b1   = (const float*)d_in[8];
    const float* g1   = (const float*)d_in[9];
    const float* be1  = (const float*)d_in[10];
    const float* m1   = (const float*)d_in[11];
    const float* v1   = (const float*)d_in[12];
    const float* W2   = (const float*)d_in[13];
    const float* b2   = (const float*)d_in[14];
    const float* g2   = (const float*)d_in[15];
    const float* be2  = (const float*)d_in[16];
    const float* m2   = (const float*)d_in[17];
    const float* v2   = (const float*)d_in[18];
    const float* Wout = (const float*)d_in[19];
    const float* bout = (const float*)d_in[20];
    float* out = (float*)d_out;
    float* ws = (float*)d_ws;

    float* h0 = ws + H_OFF;
    float* h1 = ws + H_OFF + NODE_F;
    float* hA = ws + H_OFF + 2 * NODE_F;
    float* hB = ws + H_OFF + 3 * NODE_F;
    int* bh    = (int*)(ws + BH_OFF);
    int* boffs = (int*)(ws + BOFF_OFF);
    int* bcur  = (int*)(ws + BCUR_OFF);
    int* offs  = (int*)(ws + OFFS_OFF);
    int2* csr  = (int2*)(ws + CSR_OFF);
    int2* stage = (int2*)(ws + H_OFF + 2 * NODE_F);  // aliases hA/hB (pre-node_k only)

    prep_k<<<1, 256, 0, stream>>>(W1, b1, g1, be1, m1, v1, W2, b2, g2, be2, m2, v2, ws);
    embed_k<<<(NODE_F + 255) / 256, 256, 0, stream>>>(x, Win, bin, h0);

    zero_k<<<(NBK + 255) / 256, 256, 0, stream>>>(bh, NBK);
    bhist_k<<<NBLK_S, 256, 0, stream>>>(ei, bh);
    bscan_k<<<1, 1024, 0, stream>>>(bh, boffs, bcur);
    bscatter_k<<<NBLK_S, 256, 0, stream>>>(ei, eatt, bcur, stage);
    bsort2_k<<<NBK, 256, 0, stream>>>(boffs, stage, offs, csr);

    const int waves = (N_NODES + NPW - 1) / NPW;       // 12500
    const int eblocks = (waves + 3) / 4;               // 3125
    float* cur = h0;
    float* nxt = h1;
    for (int l = 0; l < L_LAYERS; ++l) {
        node_k<<<(NODE_F + 1023) / 1024, 1024, 0, stream>>>(cur, ws, l, hA, hB);
        edge_mfma_k<<<eblocks, 256, 0, stream>>>(offs, csr, ws, l, cur, hA, hB, nxt);
        float* tmp = cur; cur = nxt; nxt = tmp;
    }

    head_k<<<1, 1024, 0, stream>>>(cur, cand, batch, Wout, bout, out);
}

// Round 9
// 329.943 us; speedup vs baseline: 1.3079x; 1.1745x over previous
//
#include <hip/hip_runtime.h>
#include <hip/hip_bf16.h>

#define N_NODES 50000
#define N_EDGES 1600000
#define N_CAND  1000
#define N_GRAPHS 50
#define EMB 32
#define L_LAYERS 4

#define BSH 8
#define BNODES 256
#define NBK ((N_NODES + BNODES - 1) >> BSH)    // 196 buckets of 256 nodes
#define STILE 4096
#define NBLK_S ((N_EDGES + STILE - 1) / STILE) // 391

#define NPW 4  // nodes per wave in edge kernel

#define W1A_OFF 0
#define W1B_OFF 4096
#define W2_OFF  8192
#define WE_OFF  12288
#define C1_OFF  12416
#define C2_OFF  12544
#define H_OFF   12800
#define NODE_F  (N_NODES * EMB)

// float-indexed layout: h0, h1, hA (fp32, NODE_F each), hB (fp16, NODE_F halfs)
#define BH_OFF    (H_OFF + 4 * NODE_F)                   // int[NBK]
#define BOFF_OFF  (BH_OFF + NBK)                         // int[NBK+1]
#define BCUR_OFF  (BOFF_OFF + NBK + 1)                   // int[NBK]
#define OFFS_OFF  (BCUR_OFF + NBK)                       // int[N_NODES+1]
#define CSR_OFF   (((OFFS_OFF + N_NODES + 1) + 1) & ~1)  // int2[N_EDGES] node-ordered
// stage (int2[N_EDGES] = 3.2M floats) aliases h1+hA (used before node_k/edge run)

typedef float f32x4 __attribute__((ext_vector_type(4)));
typedef __bf16 bf16x8 __attribute__((ext_vector_type(8)));
typedef _Float16 f16x8 __attribute__((ext_vector_type(8)));
union BF8 { __bf16 b[8]; bf16x8 v; };

__global__ void prep_k(const float* __restrict__ W1, const float* __restrict__ b1,
                       const float* __restrict__ g1, const float* __restrict__ be1,
                       const float* __restrict__ m1, const float* __restrict__ v1,
                       const float* __restrict__ W2, const float* __restrict__ b2,
                       const float* __restrict__ g2, const float* __restrict__ be2,
                       const float* __restrict__ m2, const float* __restrict__ v2,
                       float* __restrict__ ws) {
    int t = threadIdx.x;  // 256 threads, 1 block
    for (int l = 0; l < L_LAYERS; ++l) {
        for (int i = t; i < 1024; i += 256) {
            int k = i >> 5, j = i & 31;
            float s1 = g1[l * 32 + j] * rsqrtf(v1[l * 32 + j] + 1e-5f);
            float s2 = g2[l * 32 + j] * rsqrtf(v2[l * 32 + j] + 1e-5f);
            ws[W1A_OFF + l * 1024 + i] = W1[(l * 65 + k) * 32 + j] * s1;
            ws[W1B_OFF + l * 1024 + i] = W1[(l * 65 + 32 + k) * 32 + j] * s1;
            ws[W2_OFF  + l * 1024 + i] = W2[(l * 32 + k) * 32 + j] * s2;
            if (k == 0) {
                ws[WE_OFF + l * 32 + j] = W1[(l * 65 + 64) * 32 + j] * s1;
                ws[C1_OFF + l * 32 + j] = b1[l * 32 + j] * s1 + be1[l * 32 + j] - m1[l * 32 + j] * s1;
                ws[C2_OFF + l * 32 + j] = b2[l * 32 + j] * s2 + be2[l * 32 + j] - m2[l * 32 + j] * s2;
            }
        }
    }
}

__global__ void embed_k(const float* __restrict__ x, const float* __restrict__ Win,
                        const float* __restrict__ bin, float* __restrict__ h) {
    int t = blockIdx.x * blockDim.x + threadIdx.x;
    if (t >= NODE_F) return;
    int n = t >> 5, j = t & 31;
    h[t] = x[2 * n] * Win[j] + x[2 * n + 1] * Win[32 + j] + bin[j];
}

__global__ void zero_k(int* __restrict__ p, int n) {
    int t = blockIdx.x * blockDim.x + threadIdx.x;
    if (t < n) p[t] = 0;
}

// per-block LDS histogram of dst>>BSH, one global atomic per bucket per block
__global__ void bhist_k(const int* __restrict__ ei, int* __restrict__ bh) {
    __shared__ int lh[NBK];
    for (int i = threadIdx.x; i < NBK; i += 256) lh[i] = 0;
    __syncthreads();
    int tb = blockIdx.x * STILE;
#pragma unroll
    for (int i = 0; i < STILE / 256; ++i) {
        int e = tb + i * 256 + threadIdx.x;
        if (e < N_EDGES) atomicAdd(&lh[ei[N_EDGES + e] >> BSH], 1);
    }
    __syncthreads();
    for (int i = threadIdx.x; i < NBK; i += 256)
        if (lh[i]) atomicAdd(&bh[i], lh[i]);
}

// single block: exclusive scan of bh[NBK] -> boffs, bcur
__global__ void bscan_k(const int* __restrict__ bh, int* __restrict__ boffs,
                        int* __restrict__ bcur) {
    __shared__ int part[1024];
    int t = threadIdx.x;
    int s = (t < NBK) ? bh[t] : 0;
    part[t] = s;
    __syncthreads();
    for (int d = 1; d < 1024; d <<= 1) {
        int v = (t >= d) ? part[t - d] : 0;
        __syncthreads();
        part[t] += v;
        __syncthreads();
    }
    if (t < NBK) {
        int run = part[t] - s;
        boffs[t] = run;
        bcur[t] = run;
    }
    if (t == 1023) boffs[NBK] = N_EDGES;
}

// block-aggregated binning: LDS hist -> one global reserve per bucket -> direct write
__global__ void bscatter_k(const int* __restrict__ ei, const float* __restrict__ ea,
                           int* __restrict__ bcur, int2* __restrict__ stage) {
    __shared__ int lofs[NBK];
    for (int i = threadIdx.x; i < NBK; i += 256) lofs[i] = 0;
    __syncthreads();
    int tb = blockIdx.x * STILE;
#pragma unroll
    for (int i = 0; i < STILE / 256; ++i) {
        int e = tb + i * 256 + threadIdx.x;
        if (e < N_EDGES) atomicAdd(&lofs[ei[N_EDGES + e] >> BSH], 1);
    }
    __syncthreads();
    for (int bk = threadIdx.x; bk < NBK; bk += 256) {
        int c = lofs[bk];
        lofs[bk] = c ? atomicAdd(&bcur[bk], c) : 0;
    }
    __syncthreads();
#pragma unroll
    for (int i = 0; i < STILE / 256; ++i) {
        int e = tb + i * 256 + threadIdx.x;
        if (e < N_EDGES) {
            int src = ei[e], dst = ei[N_EDGES + e];
            int bk = dst >> BSH;
            int pos = atomicAdd(&lofs[bk], 1);
            int2 p;
            p.x = src | ((dst & (BNODES - 1)) << 16);
            p.y = __float_as_int(ea[e]);
            stage[pos] = p;
        }
    }
}

// one block per 256-node bucket: hist + wave-scan prefix -> offs[n]; exact scatter.
__global__ void bsort2_k(const int* __restrict__ boffs, const int2* __restrict__ stage,
                         int* __restrict__ offs, int2* __restrict__ csr) {
    __shared__ int cnt[BNODES];
    __shared__ int pre[BNODES];
    __shared__ int cur[BNODES];
    const int b = blockIdx.x;
    const int nbase = b << BSH;
    const int t = threadIdx.x;
    const int beg = boffs[b], end = boffs[b + 1];
    cnt[t] = 0;
    __syncthreads();
    for (int i = beg + t; i < end; i += 256)
        atomicAdd(&cnt[(stage[i].x >> 16) & (BNODES - 1)], 1);
    __syncthreads();
    if (t < 64) {
        int b4 = t * 4;
        int c0 = cnt[b4], c1 = cnt[b4 + 1], c2 = cnt[b4 + 2], c3 = cnt[b4 + 3];
        int s = c0 + c1 + c2 + c3;
        int run = s;
#pragma unroll
        for (int d = 1; d < 64; d <<= 1) {
            int v = __shfl_up(run, d, 64);
            if (t >= d) run += v;
        }
        int ex = run - s;  // exclusive
        pre[b4] = ex; pre[b4 + 1] = ex + c0; pre[b4 + 2] = ex + c0 + c1; pre[b4 + 3] = ex + c0 + c1 + c2;
    }
    __syncthreads();
    cur[t] = pre[t];
    {
        int n = nbase + t;
        if (n < N_NODES) offs[n] = beg + pre[t];
    }
    if (b == NBK - 1 && t == 0) offs[N_NODES] = N_EDGES;
    __syncthreads();
    for (int i = beg + t; i < end; i += 256) {
        int2 p = stage[i];
        int dloc = (p.x >> 16) & (BNODES - 1);
        int pos = beg + atomicAdd(&cur[dloc], 1);
        int2 q; q.x = p.x & 0xFFFF; q.y = p.y;
        csr[pos] = q;
    }
}

// ---------------- per-layer kernels ----------------
// hA fp32 (per-node sequential), hB fp16 (3.2MB -> per-XCD L2-resident gather target)
__global__ void node_k(const float* __restrict__ h, const float* __restrict__ ws, int l,
                       float* __restrict__ hA, _Float16* __restrict__ hB) {
    __shared__ float sA[1024], sB[1024];
    const float* W1A = ws + W1A_OFF + l * 1024;
    const float* W1B = ws + W1B_OFF + l * 1024;
    for (int i = threadIdx.x; i < 1024; i += blockDim.x) { sA[i] = W1A[i]; sB[i] = W1B[i]; }
    __syncthreads();
    int t = blockIdx.x * blockDim.x + threadIdx.x;
    if (t >= NODE_F) return;
    int j = t & 31;
    float hv = h[t];
    float a = ws[C1_OFF + l * 32 + j];
    float b = 0.f;
#pragma unroll
    for (int k = 0; k < 32; ++k) {
        float hk = __shfl(hv, k, 32);
        a += hk * sA[k * 32 + j];
        b += hk * sB[k * 32 + j];
    }
    hA[t] = a;
    hB[t] = (_Float16)b;
}

// One wave handles NPW nodes (pairs): frag0 = 16 edges of n0, frag1 = 16 edges of n1.
// A frag: lane l = row l&15, k = 8*(l>>4)+i. C/D: col=lane&15, row=4*(lane>>4)+reg.
// C2 folded into MFMA C-operand; tail predication as 0/1 float * fmaf.
__launch_bounds__(256)
__global__ void edge_mfma_k(const int* __restrict__ offs, const int2* __restrict__ csr,
                            const float* __restrict__ ws, int l,
                            const float* __restrict__ h, const float* __restrict__ hA,
                            const _Float16* __restrict__ hB, float* __restrict__ hnext) {
    const int lane = threadIdx.x & 63;
    const int wid = (blockIdx.x * 256 + threadIdx.x) >> 6;
    const int r = lane & 15;   // A row (edge slot) / D col (channel)
    const int q = lane >> 4;   // channel octet / D row quad

    const float* W2p = ws + W2_OFF + l * 1024;
    BF8 b0, b1;
#pragma unroll
    for (int i = 0; i < 8; ++i) {
        b0.b[i] = (__bf16)W2p[(8 * q + i) * 32 + r];
        b1.b[i] = (__bf16)W2p[(8 * q + i) * 32 + 16 + r];
    }
    const float c2a = ws[C2_OFF + l * 32 + r];
    const float c2b = ws[C2_OFF + l * 32 + 16 + r];
    const f32x4 zc0 = {c2a, c2a, c2a, c2a};
    const f32x4 zc1 = {c2b, c2b, c2b, c2b};
    const f32x4 we0 = *(const f32x4*)(ws + WE_OFF + l * 32 + 8 * q);
    const f32x4 we1 = *(const f32x4*)(ws + WE_OFF + l * 32 + 8 * q + 4);

    const int nbase = wid * NPW;
#pragma unroll
    for (int ni = 0; ni < NPW; ni += 2) {
        const int n0 = nbase + ni;
        if (n0 >= N_NODES) return;
        const int n1 = n0 + 1;
        const bool has1 = (n1 < N_NODES);
        const int o0 = offs[n0];
        const int o1 = offs[n0 + 1];
        const int o2 = has1 ? offs[n1 + 1] : o1;

        const f32x4 hA00 = *(const f32x4*)(hA + n0 * 32 + 8 * q);
        const f32x4 hA01 = *(const f32x4*)(hA + n0 * 32 + 8 * q + 4);
        const f32x4 hA10 = has1 ? *(const f32x4*)(hA + n1 * 32 + 8 * q) : zc0;
        const f32x4 hA11 = has1 ? *(const f32x4*)(hA + n1 * 32 + 8 * q + 4) : zc0;

        float ns00 = 0.f, ns01 = 0.f, ns10 = 0.f, ns11 = 0.f;
        const int d0 = o1 - o0, d1 = o2 - o1;
        int nit = (d0 + 15) >> 4;
        int nit1 = (d1 + 15) >> 4;
        if (nit1 > nit) nit = nit1;

        int eb0 = o0, eb1 = o1;
        for (int it = 0; it < nit; ++it, eb0 += 16, eb1 += 16) {
            int e0 = eb0 + r; e0 = (e0 < o1 - 1) ? e0 : (o1 - 1); e0 = (e0 > 0) ? e0 : 0;
            int e1 = eb1 + r; e1 = (e1 < o2 - 1) ? e1 : (o2 - 1); e1 = (e1 > 0) ? e1 : 0;
            int2 p0 = csr[e0];
            int2 p1 = csr[e1];
            int s0 = p0.x; float ea0 = __int_as_float(p0.y);
            int s1 = p1.x; float ea1 = __int_as_float(p1.y);
            const f16x8 hb0 = *(const f16x8*)(hB + s0 * 32 + 8 * q);
            const f16x8 hb1 = *(const f16x8*)(hB + s1 * 32 + 8 * q);
            BF8 a0, a1;
#pragma unroll
            for (int i = 0; i < 4; ++i) {
                a0.b[i]     = (__bf16)fmaxf(hA00[i] + (float)hb0[i]     + ea0 * we0[i], 0.f);
                a0.b[i + 4] = (__bf16)fmaxf(hA01[i] + (float)hb0[i + 4] + ea0 * we1[i], 0.f);
                a1.b[i]     = (__bf16)fmaxf(hA10[i] + (float)hb1[i]     + ea1 * we0[i], 0.f);
                a1.b[i + 4] = (__bf16)fmaxf(hA11[i] + (float)hb1[i + 4] + ea1 * we1[i], 0.f);
            }
            f32x4 acc00 = __builtin_amdgcn_mfma_f32_16x16x32_bf16(a0.v, b0.v, zc0, 0, 0, 0);
            f32x4 acc01 = __builtin_amdgcn_mfma_f32_16x16x32_bf16(a0.v, b1.v, zc1, 0, 0, 0);
            f32x4 acc10 = __builtin_amdgcn_mfma_f32_16x16x32_bf16(a1.v, b0.v, zc0, 0, 0, 0);
            f32x4 acc11 = __builtin_amdgcn_mfma_f32_16x16x32_bf16(a1.v, b1.v, zc1, 0, 0, 0);
            int nr0 = o1 - eb0;   // rows valid if row < nr0
            int nr1 = o2 - eb1;
#pragma unroll
            for (int reg = 0; reg < 4; ++reg) {
                int row = 4 * q + reg;
                float m0 = (row < nr0) ? 1.f : 0.f;
                float m1 = (row < nr1) ? 1.f : 0.f;
                ns00 = fmaf(m0, fmaxf(acc00[reg], 0.f), ns00);
                ns01 = fmaf(m0, fmaxf(acc01[reg], 0.f), ns01);
                ns10 = fmaf(m1, fmaxf(acc10[reg], 0.f), ns10);
                ns11 = fmaf(m1, fmaxf(acc11[reg], 0.f), ns11);
            }
        }
        ns00 += __shfl_xor(ns00, 16, 64);
        ns00 += __shfl_xor(ns00, 32, 64);
        ns01 += __shfl_xor(ns01, 16, 64);
        ns01 += __shfl_xor(ns01, 32, 64);
        ns10 += __shfl_xor(ns10, 16, 64);
        ns10 += __shfl_xor(ns10, 32, 64);
        ns11 += __shfl_xor(ns11, 16, 64);
        ns11 += __shfl_xor(ns11, 32, 64);
        int ll = lane & 31;
        if (lane < 32) {
            float base = h[n0 * 32 + ll];
            hnext[n0 * 32 + ll] = base + ((ll & 16) ? ns01 : ns00);
        } else if (has1) {
            float base = h[n1 * 32 + ll];
            hnext[n1 * 32 + ll] = base + ((ll & 16) ? ns11 : ns10);
        }
    }
}

__global__ void head_k(const float* __restrict__ h, const int* __restrict__ cand,
                       const int* __restrict__ batch, const float* __restrict__ Wout,
                       const float* __restrict__ bout, float* __restrict__ out) {
    __shared__ float Lg[N_CAND];
    __shared__ int Sg[N_CAND];
    __shared__ float gm[N_GRAPHS], gs[N_GRAPHS];
    int t = threadIdx.x;  // 1024
    if (t < N_CAND) {
        int c = cand[t];
        float acc = bout[0];
#pragma unroll
        for (int j = 0; j < 32; ++j) acc += h[c * 32 + j] * Wout[j];
        Lg[t] = acc;
        Sg[t] = batch[c];
    }
    __syncthreads();
    if (t < 16 * N_GRAPHS) {
        int g = t >> 4, s = t & 15;
        float m = -1e30f;
        for (int i = s; i < N_CAND; i += 16)
            if (Sg[i] == g) m = fmaxf(m, Lg[i]);
#pragma unroll
        for (int d = 1; d < 16; d <<= 1) m = fmaxf(m, __shfl_xor(m, d, 64));
        float ssum = 0.f;
        for (int i = s; i < N_CAND; i += 16)
            if (Sg[i] == g) ssum += expf(Lg[i] - m);
#pragma unroll
        for (int d = 1; d < 16; d <<= 1) ssum += __shfl_xor(ssum, d, 64);
        if (s == 0) { gm[g] = m; gs[g] = logf(ssum); }
    }
    __syncthreads();
    if (t < N_CAND) out[t] = Lg[t] - gm[Sg[t]] - gs[Sg[t]];
}

extern "C" void kernel_launch(void* const* d_in, const int* in_sizes, int n_in,
                              void* d_out, int out_size, void* d_ws, size_t ws_size,
                              hipStream_t stream) {
    const float* x    = (const float*)d_in[0];
    const int*   ei   = (const int*)d_in[1];
    const float* eatt = (const float*)d_in[2];
    const int*   cand = (const int*)d_in[3];
    const int*   batch= (const int*)d_in[4];
    const float* Win  = (const float*)d_in[5];
    const float* bin  = (const float*)d_in[6];
    const float* W1   = (const float*)d_in[7];
    const float* b1   = (const float*)d_in[8];
    const float* g1   = (const float*)d_in[9];
    const float* be1  = (const float*)d_in[10];
    const float* m1   = (const float*)d_in[11];
    const float* v1   = (const float*)d_in[12];
    const float* W2   = (const float*)d_in[13];
    const float* b2   = (const float*)d_in[14];
    const float* g2   = (const float*)d_in[15];
    const float* be2  = (const float*)d_in[16];
    const float* m2   = (const float*)d_in[17];
    const float* v2   = (const float*)d_in[18];
    const float* Wout = (const float*)d_in[19];
    const float* bout = (const float*)d_in[20];
    float* out = (float*)d_out;
    float* ws = (float*)d_ws;

    float* h0 = ws + H_OFF;
    float* h1 = ws + H_OFF + NODE_F;
    float* hA = ws + H_OFF + 2 * NODE_F;
    _Float16* hB = (_Float16*)(ws + H_OFF + 3 * NODE_F);
    int* bh    = (int*)(ws + BH_OFF);
    int* boffs = (int*)(ws + BOFF_OFF);
    int* bcur  = (int*)(ws + BCUR_OFF);
    int* offs  = (int*)(ws + OFFS_OFF);
    int2* csr  = (int2*)(ws + CSR_OFF);
    int2* stage = (int2*)(ws + H_OFF + NODE_F);  // aliases h1+hA (pre-node_k only)

    prep_k<<<1, 256, 0, stream>>>(W1, b1, g1, be1, m1, v1, W2, b2, g2, be2, m2, v2, ws);
    embed_k<<<(NODE_F + 255) / 256, 256, 0, stream>>>(x, Win, bin, h0);

    zero_k<<<(NBK + 255) / 256, 256, 0, stream>>>(bh, NBK);
    bhist_k<<<NBLK_S, 256, 0, stream>>>(ei, bh);
    bscan_k<<<1, 1024, 0, stream>>>(bh, boffs, bcur);
    bscatter_k<<<NBLK_S, 256, 0, stream>>>(ei, eatt, bcur, stage);
    bsort2_k<<<NBK, 256, 0, stream>>>(boffs, stage, offs, csr);

    const int waves = (N_NODES + NPW - 1) / NPW;       // 12500
    const int eblocks = (waves + 3) / 4;               // 3125
    float* cur = h0;
    float* nxt = h1;
    for (int l = 0; l < L_LAYERS; ++l) {
        node_k<<<(NODE_F + 1023) / 1024, 1024, 0, stream>>>(cur, ws, l, hA, hB);
        edge_mfma_k<<<eblocks, 256, 0, stream>>>(offs, csr, ws, l, cur, hA, hB, nxt);
        float* tmp = cur; cur = nxt; nxt = tmp;
    }

    head_k<<<1, 1024, 0, stream>>>(cur, cand, batch, Wout, bout, out);
}

// Round 10
// 305.372 us; speedup vs baseline: 1.4132x; 1.0805x over previous
//
#include <hip/hip_runtime.h>
#include <hip/hip_bf16.h>

#define N_NODES 50000
#define N_EDGES 1600000
#define N_CAND  1000
#define N_GRAPHS 50
#define EMB 32
#define L_LAYERS 4

#define BSH 8
#define BNODES 256
#define NBK ((N_NODES + BNODES - 1) >> BSH)    // 196 buckets of 256 nodes
#define STILE 4096
#define NBLK_S ((N_EDGES + STILE - 1) / STILE) // 391

#define NPW 8  // nodes per wave in edge kernel (4 pairs, rolled)

#define W1A_OFF 0
#define W1B_OFF 4096
#define W2_OFF  8192
#define WE_OFF  12288
#define C1_OFF  12416
#define C2_OFF  12544
#define W2H_OFF 12672   // f16[4][1024] = 2048 floats
#define WEH_OFF 14720   // f16[4][32]   = 64 floats
#define H_OFF   14848
#define NODE_F  (N_NODES * EMB)

// float-indexed: h0, h1 (fp32 NODE_F each), hA16 (f16 NODE_F = NODE_F/2 floats), hB16 (same)
#define BH_OFF    (H_OFF + 3 * NODE_F)                   // int[NBK]
#define BOFF_OFF  (BH_OFF + NBK)                         // int[NBK+1]
#define BCUR_OFF  (BOFF_OFF + NBK + 1)                   // int[NBK]
#define OFFS_OFF  (BCUR_OFF + NBK)                       // int[N_NODES+1]
#define CSR_OFF   (((OFFS_OFF + N_NODES + 1) + 1) & ~1)  // int2[N_EDGES] node-ordered
// stage (int2[N_EDGES] = 2*NODE_F floats) aliases [h1, hA16, hB16] (pre-node_k only)

typedef float f32x4 __attribute__((ext_vector_type(4)));
typedef _Float16 f16x8 __attribute__((ext_vector_type(8)));

__global__ void prep_k(const float* __restrict__ W1, const float* __restrict__ b1,
                       const float* __restrict__ g1, const float* __restrict__ be1,
                       const float* __restrict__ m1, const float* __restrict__ v1,
                       const float* __restrict__ W2, const float* __restrict__ b2,
                       const float* __restrict__ g2, const float* __restrict__ be2,
                       const float* __restrict__ m2, const float* __restrict__ v2,
                       float* __restrict__ ws) {
    int t = threadIdx.x;  // 256 threads, 1 block
    _Float16* W2H = (_Float16*)(ws + W2H_OFF);
    _Float16* WEH = (_Float16*)(ws + WEH_OFF);
    for (int l = 0; l < L_LAYERS; ++l) {
        for (int i = t; i < 1024; i += 256) {
            int k = i >> 5, j = i & 31;
            float s1 = g1[l * 32 + j] * rsqrtf(v1[l * 32 + j] + 1e-5f);
            float s2 = g2[l * 32 + j] * rsqrtf(v2[l * 32 + j] + 1e-5f);
            ws[W1A_OFF + l * 1024 + i] = W1[(l * 65 + k) * 32 + j] * s1;
            ws[W1B_OFF + l * 1024 + i] = W1[(l * 65 + 32 + k) * 32 + j] * s1;
            float w2v = W2[(l * 32 + k) * 32 + j] * s2;
            ws[W2_OFF + l * 1024 + i] = w2v;
            W2H[l * 1024 + i] = (_Float16)w2v;
            if (k == 0) {
                float wev = W1[(l * 65 + 64) * 32 + j] * s1;
                ws[WE_OFF + l * 32 + j] = wev;
                WEH[l * 32 + j] = (_Float16)wev;
                ws[C1_OFF + l * 32 + j] = b1[l * 32 + j] * s1 + be1[l * 32 + j] - m1[l * 32 + j] * s1;
                ws[C2_OFF + l * 32 + j] = b2[l * 32 + j] * s2 + be2[l * 32 + j] - m2[l * 32 + j] * s2;
            }
        }
    }
}

__global__ void embed_k(const float* __restrict__ x, const float* __restrict__ Win,
                        const float* __restrict__ bin, float* __restrict__ h) {
    int t = blockIdx.x * blockDim.x + threadIdx.x;
    if (t >= NODE_F) return;
    int n = t >> 5, j = t & 31;
    h[t] = x[2 * n] * Win[j] + x[2 * n + 1] * Win[32 + j] + bin[j];
}

__global__ void zero_k(int* __restrict__ p, int n) {
    int t = blockIdx.x * blockDim.x + threadIdx.x;
    if (t < n) p[t] = 0;
}

// per-block LDS histogram of dst>>BSH, one global atomic per bucket per block
__global__ void bhist_k(const int* __restrict__ ei, int* __restrict__ bh) {
    __shared__ int lh[NBK];
    for (int i = threadIdx.x; i < NBK; i += 512) lh[i] = 0;
    __syncthreads();
    int tb = blockIdx.x * STILE;
#pragma unroll
    for (int i = 0; i < STILE / 512; ++i) {
        int e = tb + i * 512 + threadIdx.x;
        if (e < N_EDGES) atomicAdd(&lh[ei[N_EDGES + e] >> BSH], 1);
    }
    __syncthreads();
    for (int i = threadIdx.x; i < NBK; i += 512)
        if (lh[i]) atomicAdd(&bh[i], lh[i]);
}

// single block: exclusive scan of bh[NBK] -> boffs, bcur
__global__ void bscan_k(const int* __restrict__ bh, int* __restrict__ boffs,
                        int* __restrict__ bcur) {
    __shared__ int part[1024];
    int t = threadIdx.x;
    int s = (t < NBK) ? bh[t] : 0;
    part[t] = s;
    __syncthreads();
    for (int d = 1; d < 1024; d <<= 1) {
        int v = (t >= d) ? part[t - d] : 0;
        __syncthreads();
        part[t] += v;
        __syncthreads();
    }
    if (t < NBK) {
        int run = part[t] - s;
        boffs[t] = run;
        bcur[t] = run;
    }
    if (t == 1023) boffs[NBK] = N_EDGES;
}

// block-aggregated binning: LDS hist -> one global reserve per bucket -> direct write
__global__ void bscatter_k(const int* __restrict__ ei, const float* __restrict__ ea,
                           int* __restrict__ bcur, int2* __restrict__ stage) {
    __shared__ int lofs[NBK];
    for (int i = threadIdx.x; i < NBK; i += 512) lofs[i] = 0;
    __syncthreads();
    int tb = blockIdx.x * STILE;
#pragma unroll
    for (int i = 0; i < STILE / 512; ++i) {
        int e = tb + i * 512 + threadIdx.x;
        if (e < N_EDGES) atomicAdd(&lofs[ei[N_EDGES + e] >> BSH], 1);
    }
    __syncthreads();
    for (int bk = threadIdx.x; bk < NBK; bk += 512) {
        int c = lofs[bk];
        lofs[bk] = c ? atomicAdd(&bcur[bk], c) : 0;
    }
    __syncthreads();
#pragma unroll
    for (int i = 0; i < STILE / 512; ++i) {
        int e = tb + i * 512 + threadIdx.x;
        if (e < N_EDGES) {
            int src = ei[e], dst = ei[N_EDGES + e];
            int bk = dst >> BSH;
            int pos = atomicAdd(&lofs[bk], 1);
            int2 p;
            p.x = src | ((dst & (BNODES - 1)) << 16);
            p.y = __float_as_int(ea[e]);
            stage[pos] = p;
        }
    }
}

// one block per 256-node bucket: hist + wave-scan prefix -> offs[n]; exact scatter.
__global__ void bsort2_k(const int* __restrict__ boffs, const int2* __restrict__ stage,
                         int* __restrict__ offs, int2* __restrict__ csr) {
    __shared__ int cnt[BNODES];
    __shared__ int pre[BNODES];
    __shared__ int cur[BNODES];
    const int b = blockIdx.x;
    const int nbase = b << BSH;
    const int t = threadIdx.x;
    const int beg = boffs[b], end = boffs[b + 1];
    cnt[t] = 0;
    __syncthreads();
    for (int i = beg + t; i < end; i += 256)
        atomicAdd(&cnt[(stage[i].x >> 16) & (BNODES - 1)], 1);
    __syncthreads();
    if (t < 64) {
        int b4 = t * 4;
        int c0 = cnt[b4], c1 = cnt[b4 + 1], c2 = cnt[b4 + 2], c3 = cnt[b4 + 3];
        int s = c0 + c1 + c2 + c3;
        int run = s;
#pragma unroll
        for (int d = 1; d < 64; d <<= 1) {
            int v = __shfl_up(run, d, 64);
            if (t >= d) run += v;
        }
        int ex = run - s;  // exclusive
        pre[b4] = ex; pre[b4 + 1] = ex + c0; pre[b4 + 2] = ex + c0 + c1; pre[b4 + 3] = ex + c0 + c1 + c2;
    }
    __syncthreads();
    cur[t] = pre[t];
    {
        int n = nbase + t;
        if (n < N_NODES) offs[n] = beg + pre[t];
    }
    if (b == NBK - 1 && t == 0) offs[N_NODES] = N_EDGES;
    __syncthreads();
    for (int i = beg + t; i < end; i += 256) {
        int2 p = stage[i];
        int dloc = (p.x >> 16) & (BNODES - 1);
        int pos = beg + atomicAdd(&cur[dloc], 1);
        int2 q; q.x = p.x & 0xFFFF; q.y = p.y;
        csr[pos] = q;
    }
}

// ---------------- per-layer kernels ----------------
// hA, hB both fp16 (each 3.2MB -> L2-resident gather/sequential targets)
__global__ void node_k(const float* __restrict__ h, const float* __restrict__ ws, int l,
                       _Float16* __restrict__ hA, _Float16* __restrict__ hB) {
    __shared__ float sA[1024], sB[1024];
    const float* W1A = ws + W1A_OFF + l * 1024;
    const float* W1B = ws + W1B_OFF + l * 1024;
    for (int i = threadIdx.x; i < 1024; i += blockDim.x) { sA[i] = W1A[i]; sB[i] = W1B[i]; }
    __syncthreads();
    int t = blockIdx.x * blockDim.x + threadIdx.x;
    if (t >= NODE_F) return;
    int j = t & 31;
    float hv = h[t];
    float a = ws[C1_OFF + l * 32 + j];
    float b = 0.f;
#pragma unroll
    for (int k = 0; k < 32; ++k) {
        float hk = __shfl(hv, k, 32);
        a += hk * sA[k * 32 + j];
        b += hk * sB[k * 32 + j];
    }
    hA[t] = (_Float16)a;
    hB[t] = (_Float16)b;
}

// One wave handles NPW nodes as pairs (rolled loop): frag0 = 16 edges of n0, frag1 = n1.
// fp16 A/B frags -> mfma_f32_16x16x32_f16. C2 folded into MFMA C-operand.
// A frag: lane l = row l&15, k = 8*(l>>4)+i. C/D: col=lane&15, row=4*(lane>>4)+reg.
__launch_bounds__(256, 6)
__global__ void edge_mfma_k(const int* __restrict__ offs, const int2* __restrict__ csr,
                            const float* __restrict__ ws, int l,
                            const float* __restrict__ h, const _Float16* __restrict__ hA,
                            const _Float16* __restrict__ hB, float* __restrict__ hnext) {
    const int lane = threadIdx.x & 63;
    const int wid = (blockIdx.x * 256 + threadIdx.x) >> 6;
    const int r = lane & 15;   // A row (edge slot) / D col (channel)
    const int q = lane >> 4;   // channel octet / D row quad

    const _Float16* W2H = (const _Float16*)(ws + W2H_OFF);
    f16x8 b0, b1;
#pragma unroll
    for (int i = 0; i < 8; ++i) {
        b0[i] = W2H[l * 1024 + (8 * q + i) * 32 + r];
        b1[i] = W2H[l * 1024 + (8 * q + i) * 32 + 16 + r];
    }
    const float c2a = ws[C2_OFF + l * 32 + r];
    const float c2b = ws[C2_OFF + l * 32 + 16 + r];
    const f32x4 zc0 = {c2a, c2a, c2a, c2a};
    const f32x4 zc1 = {c2b, c2b, c2b, c2b};
    const f16x8 we = *(const f16x8*)((const _Float16*)(ws + WEH_OFF) + l * 32 + 8 * q);
    const f16x8 zero8 = {};

    const int nbase = wid * NPW;
#pragma unroll 1
    for (int ni = 0; ni < NPW; ni += 2) {
        const int n0 = nbase + ni;
        if (n0 >= N_NODES) return;
        const int n1 = n0 + 1;
        const bool has1 = (n1 < N_NODES);
        const int o0 = offs[n0];
        const int o1 = offs[n0 + 1];
        const int o2 = has1 ? offs[n1 + 1] : o1;

        const f16x8 hA0 = *(const f16x8*)(hA + n0 * 32 + 8 * q);
        const f16x8 hA1 = has1 ? *(const f16x8*)(hA + n1 * 32 + 8 * q) : zero8;

        float ns00 = 0.f, ns01 = 0.f, ns10 = 0.f, ns11 = 0.f;
        const int d0 = o1 - o0, d1 = o2 - o1;
        int nit = (d0 + 15) >> 4;
        int nit1 = (d1 + 15) >> 4;
        if (nit1 > nit) nit = nit1;

        if (nit > 0) {
            int eb0 = o0, eb1 = o1;
            int e0 = eb0 + r; e0 = (e0 < o1 - 1) ? e0 : (o1 - 1); e0 = (e0 > 0) ? e0 : 0;
            int e1 = eb1 + r; e1 = (e1 < o2 - 1) ? e1 : (o2 - 1); e1 = (e1 > 0) ? e1 : 0;
            int2 p0 = csr[e0];
            int2 p1 = csr[e1];
            for (int it = 0; it < nit; ++it) {
                const f16x8 hb0 = *(const f16x8*)(hB + p0.x * 32 + 8 * q);
                const f16x8 hb1 = *(const f16x8*)(hB + p1.x * 32 + 8 * q);
                _Float16 eah0 = (_Float16)__int_as_float(p0.y);
                _Float16 eah1 = (_Float16)__int_as_float(p1.y);
                int nr0 = o1 - eb0;
                int nr1 = o2 - eb1;
                eb0 += 16; eb1 += 16;
                // prefetch next chunk's csr while computing
                if (it + 1 < nit) {
                    int e0n = eb0 + r; e0n = (e0n < o1 - 1) ? e0n : (o1 - 1); e0n = (e0n > 0) ? e0n : 0;
                    int e1n = eb1 + r; e1n = (e1n < o2 - 1) ? e1n : (o2 - 1); e1n = (e1n > 0) ? e1n : 0;
                    p0 = csr[e0n];
                    p1 = csr[e1n];
                }
                f16x8 a0 = __builtin_elementwise_max(we * eah0 + (hA0 + hb0), zero8);
                f16x8 a1 = __builtin_elementwise_max(we * eah1 + (hA1 + hb1), zero8);
                f32x4 acc00 = __builtin_amdgcn_mfma_f32_16x16x32_f16(a0, b0, zc0, 0, 0, 0);
                f32x4 acc01 = __builtin_amdgcn_mfma_f32_16x16x32_f16(a0, b1, zc1, 0, 0, 0);
                f32x4 acc10 = __builtin_amdgcn_mfma_f32_16x16x32_f16(a1, b0, zc0, 0, 0, 0);
                f32x4 acc11 = __builtin_amdgcn_mfma_f32_16x16x32_f16(a1, b1, zc1, 0, 0, 0);
#pragma unroll
                for (int reg = 0; reg < 4; ++reg) {
                    int row = 4 * q + reg;
                    float m0 = (row < nr0) ? 1.f : 0.f;
                    float m1 = (row < nr1) ? 1.f : 0.f;
                    ns00 = fmaf(m0, fmaxf(acc00[reg], 0.f), ns00);
                    ns01 = fmaf(m0, fmaxf(acc01[reg], 0.f), ns01);
                    ns10 = fmaf(m1, fmaxf(acc10[reg], 0.f), ns10);
                    ns11 = fmaf(m1, fmaxf(acc11[reg], 0.f), ns11);
                }
            }
        }
        ns00 += __shfl_xor(ns00, 16, 64);
        ns00 += __shfl_xor(ns00, 32, 64);
        ns01 += __shfl_xor(ns01, 16, 64);
        ns01 += __shfl_xor(ns01, 32, 64);
        ns10 += __shfl_xor(ns10, 16, 64);
        ns10 += __shfl_xor(ns10, 32, 64);
        ns11 += __shfl_xor(ns11, 16, 64);
        ns11 += __shfl_xor(ns11, 32, 64);
        int ll = lane & 31;
        if (lane < 32) {
            float base = h[n0 * 32 + ll];
            hnext[n0 * 32 + ll] = base + ((ll & 16) ? ns01 : ns00);
        } else if (has1) {
            float base = h[n1 * 32 + ll];
            hnext[n1 * 32 + ll] = base + ((ll & 16) ? ns11 : ns10);
        }
    }
}

__global__ void head_k(const float* __restrict__ h, const int* __restrict__ cand,
                       const int* __restrict__ batch, const float* __restrict__ Wout,
                       const float* __restrict__ bout, float* __restrict__ out) {
    __shared__ float Lg[N_CAND];
    __shared__ int Sg[N_CAND];
    __shared__ float gm[N_GRAPHS], gs[N_GRAPHS];
    int t = threadIdx.x;  // 1024
    if (t < N_CAND) {
        int c = cand[t];
        float acc = bout[0];
#pragma unroll
        for (int j = 0; j < 32; ++j) acc += h[c * 32 + j] * Wout[j];
        Lg[t] = acc;
        Sg[t] = batch[c];
    }
    __syncthreads();
    if (t < 16 * N_GRAPHS) {
        int g = t >> 4, s = t & 15;
        float m = -1e30f;
        for (int i = s; i < N_CAND; i += 16)
            if (Sg[i] == g) m = fmaxf(m, Lg[i]);
#pragma unroll
        for (int d = 1; d < 16; d <<= 1) m = fmaxf(m, __shfl_xor(m, d, 64));
        float ssum = 0.f;
        for (int i = s; i < N_CAND; i += 16)
            if (Sg[i] == g) ssum += expf(Lg[i] - m);
#pragma unroll
        for (int d = 1; d < 16; d <<= 1) ssum += __shfl_xor(ssum, d, 64);
        if (s == 0) { gm[g] = m; gs[g] = logf(ssum); }
    }
    __syncthreads();
    if (t < N_CAND) out[t] = Lg[t] - gm[Sg[t]] - gs[Sg[t]];
}

extern "C" void kernel_launch(void* const* d_in, const int* in_sizes, int n_in,
                              void* d_out, int out_size, void* d_ws, size_t ws_size,
                              hipStream_t stream) {
    const float* x    = (const float*)d_in[0];
    const int*   ei   = (const int*)d_in[1];
    const float* eatt = (const float*)d_in[2];
    const int*   cand = (const int*)d_in[3];
    const int*   batch= (const int*)d_in[4];
    const float* Win  = (const float*)d_in[5];
    const float* bin  = (const float*)d_in[6];
    const float* W1   = (const float*)d_in[7];
    const float* b1   = (const float*)d_in[8];
    const float* g1   = (const float*)d_in[9];
    const float* be1  = (const float*)d_in[10];
    const float* m1   = (const float*)d_in[11];
    const float* v1   = (const float*)d_in[12];
    const float* W2   = (const float*)d_in[13];
    const float* b2   = (const float*)d_in[14];
    const float* g2   = (const float*)d_in[15];
    const float* be2  = (const float*)d_in[16];
    const float* m2   = (const float*)d_in[17];
    const float* v2   = (const float*)d_in[18];
    const float* Wout = (const float*)d_in[19];
    const float* bout = (const float*)d_in[20];
    float* out = (float*)d_out;
    float* ws = (float*)d_ws;

    float* h0 = ws + H_OFF;
    float* h1 = ws + H_OFF + NODE_F;
    _Float16* hA = (_Float16*)(ws + H_OFF + 2 * NODE_F);
    _Float16* hB = (_Float16*)(ws + H_OFF + 2 * NODE_F + NODE_F / 2);
    int* bh    = (int*)(ws + BH_OFF);
    int* boffs = (int*)(ws + BOFF_OFF);
    int* bcur  = (int*)(ws + BCUR_OFF);
    int* offs  = (int*)(ws + OFFS_OFF);
    int2* csr  = (int2*)(ws + CSR_OFF);
    int2* stage = (int2*)(ws + H_OFF + NODE_F);  // aliases h1+hA+hB (pre-node_k only)

    prep_k<<<1, 256, 0, stream>>>(W1, b1, g1, be1, m1, v1, W2, b2, g2, be2, m2, v2, ws);
    embed_k<<<(NODE_F + 255) / 256, 256, 0, stream>>>(x, Win, bin, h0);

    zero_k<<<(NBK + 255) / 256, 256, 0, stream>>>(bh, NBK);
    bhist_k<<<NBLK_S, 512, 0, stream>>>(ei, bh);
    bscan_k<<<1, 1024, 0, stream>>>(bh, boffs, bcur);
    bscatter_k<<<NBLK_S, 512, 0, stream>>>(ei, eatt, bcur, stage);
    bsort2_k<<<NBK, 256, 0, stream>>>(boffs, stage, offs, csr);

    const int waves = (N_NODES + NPW - 1) / NPW;       // 6250
    const int eblocks = (waves + 3) / 4;               // 1563
    float* cur = h0;
    float* nxt = h1;
    for (int l = 0; l < L_LAYERS; ++l) {
        node_k<<<(NODE_F + 1023) / 1024, 1024, 0, stream>>>(cur, ws, l, hA, hB);
        edge_mfma_k<<<eblocks, 256, 0, stream>>>(offs, csr, ws, l, cur, hA, hB, nxt);
        float* tmp = cur; cur = nxt; nxt = tmp;
    }

    head_k<<<1, 1024, 0, stream>>>(cur, cand, batch, Wout, bout, out);
}

// Round 11
// 300.927 us; speedup vs baseline: 1.4341x; 1.0148x over previous
//
#include <hip/hip_runtime.h>
#include <hip/hip_bf16.h>

#define N_NODES 50000
#define N_EDGES 1600000
#define N_CAND  1000
#define N_GRAPHS 50
#define EMB 32
#define L_LAYERS 4

#define BSH 8
#define BNODES 256
#define NBK ((N_NODES + BNODES - 1) >> BSH)    // 196 buckets of 256 nodes
#define STILE 4096
#define NBLK_S ((N_EDGES + STILE - 1) / STILE) // 391

#define NPW 8  // nodes per wave in edge kernel (4 pairs, rolled)

#define W1A_OFF 0
#define W1B_OFF 4096
#define W2_OFF  8192
#define WE_OFF  12288
#define C1_OFF  12416
#define C2_OFF  12544
#define W2H_OFF 12672   // f16[4][1024] = 2048 floats
#define WEH_OFF 14720   // f16[4][32]   = 64 floats
#define H_OFF   14848
#define NODE_F  (N_NODES * EMB)

// float-indexed: h0, h1 (fp32 NODE_F each), hA16 (f16 NODE_F = NODE_F/2 floats), hB16 (same)
#define BH_OFF    (H_OFF + 3 * NODE_F)                   // int[NBK]
#define BOFF_OFF  (BH_OFF + NBK)                         // int[NBK+1]
#define BCUR_OFF  (BOFF_OFF + NBK + 1)                   // int[NBK]
#define OFFS_OFF  (BCUR_OFF + NBK)                       // int[N_NODES+1]
#define CSR_OFF   (OFFS_OFF + N_NODES + 1)               // int[N_EDGES] (src|f16ea<<16)
// stage (int2[N_EDGES] = 2*NODE_F floats) aliases [h1, hA16, hB16] (pre-node_k only)

typedef float f32x4 __attribute__((ext_vector_type(4)));
typedef _Float16 f16x8 __attribute__((ext_vector_type(8)));

union HU { unsigned short u; _Float16 f; };
static __device__ __forceinline__ _Float16 h16(unsigned short u) { HU c; c.u = u; return c.f; }
static __device__ __forceinline__ unsigned short u16(_Float16 f) { HU c; c.f = f; return c.u; }

__global__ void prep_k(const float* __restrict__ W1, const float* __restrict__ b1,
                       const float* __restrict__ g1, const float* __restrict__ be1,
                       const float* __restrict__ m1, const float* __restrict__ v1,
                       const float* __restrict__ W2, const float* __restrict__ b2,
                       const float* __restrict__ g2, const float* __restrict__ be2,
                       const float* __restrict__ m2, const float* __restrict__ v2,
                       float* __restrict__ ws) {
    int t = threadIdx.x;  // 256 threads, 1 block
    _Float16* W2H = (_Float16*)(ws + W2H_OFF);
    _Float16* WEH = (_Float16*)(ws + WEH_OFF);
    for (int l = 0; l < L_LAYERS; ++l) {
        for (int i = t; i < 1024; i += 256) {
            int k = i >> 5, j = i & 31;
            float s1 = g1[l * 32 + j] * rsqrtf(v1[l * 32 + j] + 1e-5f);
            float s2 = g2[l * 32 + j] * rsqrtf(v2[l * 32 + j] + 1e-5f);
            ws[W1A_OFF + l * 1024 + i] = W1[(l * 65 + k) * 32 + j] * s1;
            ws[W1B_OFF + l * 1024 + i] = W1[(l * 65 + 32 + k) * 32 + j] * s1;
            float w2v = W2[(l * 32 + k) * 32 + j] * s2;
            ws[W2_OFF + l * 1024 + i] = w2v;
            W2H[l * 1024 + i] = (_Float16)w2v;
            if (k == 0) {
                float wev = W1[(l * 65 + 64) * 32 + j] * s1;
                ws[WE_OFF + l * 32 + j] = wev;
                WEH[l * 32 + j] = (_Float16)wev;
                ws[C1_OFF + l * 32 + j] = b1[l * 32 + j] * s1 + be1[l * 32 + j] - m1[l * 32 + j] * s1;
                ws[C2_OFF + l * 32 + j] = b2[l * 32 + j] * s2 + be2[l * 32 + j] - m2[l * 32 + j] * s2;
            }
        }
    }
}

// fused: h0 = x@Win+bin ; hA/hB for layer 0
__global__ void embed_node_k(const float* __restrict__ x, const float* __restrict__ Win,
                             const float* __restrict__ bin, const float* __restrict__ ws,
                             float* __restrict__ h, _Float16* __restrict__ hA,
                             _Float16* __restrict__ hB) {
    __shared__ float sA[1024], sB[1024];
    for (int i = threadIdx.x; i < 1024; i += blockDim.x) {
        sA[i] = ws[W1A_OFF + i];
        sB[i] = ws[W1B_OFF + i];
    }
    __syncthreads();
    int t = blockIdx.x * blockDim.x + threadIdx.x;
    if (t >= NODE_F) return;
    int n = t >> 5, j = t & 31;
    float hv = x[2 * n] * Win[j] + x[2 * n + 1] * Win[32 + j] + bin[j];
    h[t] = hv;
    float a = ws[C1_OFF + j];
    float b = 0.f;
#pragma unroll
    for (int k = 0; k < 32; ++k) {
        float hk = __shfl(hv, k, 32);
        a += hk * sA[k * 32 + j];
        b += hk * sB[k * 32 + j];
    }
    hA[t] = (_Float16)a;
    hB[t] = (_Float16)b;
}

__global__ void zero_k(int* __restrict__ p, int n) {
    int t = blockIdx.x * blockDim.x + threadIdx.x;
    if (t < n) p[t] = 0;
}

// per-block LDS histogram of dst>>BSH, one global atomic per bucket per block
__global__ void bhist_k(const int* __restrict__ ei, int* __restrict__ bh) {
    __shared__ int lh[NBK];
    for (int i = threadIdx.x; i < NBK; i += 512) lh[i] = 0;
    __syncthreads();
    int tb = blockIdx.x * STILE;
#pragma unroll
    for (int i = 0; i < STILE / 512; ++i) {
        int e = tb + i * 512 + threadIdx.x;
        if (e < N_EDGES) atomicAdd(&lh[ei[N_EDGES + e] >> BSH], 1);
    }
    __syncthreads();
    for (int i = threadIdx.x; i < NBK; i += 512)
        if (lh[i]) atomicAdd(&bh[i], lh[i]);
}

// single block: exclusive scan of bh[NBK] -> boffs, bcur
__global__ void bscan_k(const int* __restrict__ bh, int* __restrict__ boffs,
                        int* __restrict__ bcur) {
    __shared__ int part[1024];
    int t = threadIdx.x;
    int s = (t < NBK) ? bh[t] : 0;
    part[t] = s;
    __syncthreads();
    for (int d = 1; d < 1024; d <<= 1) {
        int v = (t >= d) ? part[t - d] : 0;
        __syncthreads();
        part[t] += v;
        __syncthreads();
    }
    if (t < NBK) {
        int run = part[t] - s;
        boffs[t] = run;
        bcur[t] = run;
    }
    if (t == 1023) boffs[NBK] = N_EDGES;
}

// block-aggregated binning: LDS hist -> one global reserve per bucket -> direct write
__global__ void bscatter_k(const int* __restrict__ ei, const float* __restrict__ ea,
                           int* __restrict__ bcur, int2* __restrict__ stage) {
    __shared__ int lofs[NBK];
    for (int i = threadIdx.x; i < NBK; i += 512) lofs[i] = 0;
    __syncthreads();
    int tb = blockIdx.x * STILE;
#pragma unroll
    for (int i = 0; i < STILE / 512; ++i) {
        int e = tb + i * 512 + threadIdx.x;
        if (e < N_EDGES) atomicAdd(&lofs[ei[N_EDGES + e] >> BSH], 1);
    }
    __syncthreads();
    for (int bk = threadIdx.x; bk < NBK; bk += 512) {
        int c = lofs[bk];
        lofs[bk] = c ? atomicAdd(&bcur[bk], c) : 0;
    }
    __syncthreads();
#pragma unroll
    for (int i = 0; i < STILE / 512; ++i) {
        int e = tb + i * 512 + threadIdx.x;
        if (e < N_EDGES) {
            int src = ei[e], dst = ei[N_EDGES + e];
            int bk = dst >> BSH;
            int pos = atomicAdd(&lofs[bk], 1);
            int2 p;
            p.x = src | ((dst & (BNODES - 1)) << 16);
            p.y = __float_as_int(ea[e]);
            stage[pos] = p;
        }
    }
}

// one block per 256-node bucket: hist + wave-scan prefix -> offs[n]; exact scatter.
// csr entry packed as src(16b) | f16(ea)(16b).
__global__ void bsort2_k(const int* __restrict__ boffs, const int2* __restrict__ stage,
                         int* __restrict__ offs, int* __restrict__ csr) {
    __shared__ int cnt[BNODES];
    __shared__ int pre[BNODES];
    __shared__ int cur[BNODES];
    const int b = blockIdx.x;
    const int nbase = b << BSH;
    const int t = threadIdx.x;  // 512
    const int beg = boffs[b], end = boffs[b + 1];
    if (t < BNODES) cnt[t] = 0;
    __syncthreads();
    for (int i = beg + t; i < end; i += 512)
        atomicAdd(&cnt[(stage[i].x >> 16) & (BNODES - 1)], 1);
    __syncthreads();
    if (t < 64) {
        int b4 = t * 4;
        int c0 = cnt[b4], c1 = cnt[b4 + 1], c2 = cnt[b4 + 2], c3 = cnt[b4 + 3];
        int s = c0 + c1 + c2 + c3;
        int run = s;
#pragma unroll
        for (int d = 1; d < 64; d <<= 1) {
            int v = __shfl_up(run, d, 64);
            if (t >= d) run += v;
        }
        int ex = run - s;  // exclusive
        pre[b4] = ex; pre[b4 + 1] = ex + c0; pre[b4 + 2] = ex + c0 + c1; pre[b4 + 3] = ex + c0 + c1 + c2;
    }
    __syncthreads();
    if (t < BNODES) {
        cur[t] = pre[t];
        int n = nbase + t;
        if (n < N_NODES) offs[n] = beg + pre[t];
    }
    if (b == NBK - 1 && t == 0) offs[N_NODES] = N_EDGES;
    __syncthreads();
    for (int i = beg + t; i < end; i += 512) {
        int2 p = stage[i];
        int dloc = (p.x >> 16) & (BNODES - 1);
        int pos = beg + atomicAdd(&cur[dloc], 1);
        unsigned short eh = u16((_Float16)__int_as_float(p.y));
        csr[pos] = (p.x & 0xFFFF) | ((int)eh << 16);
    }
}

// ---------------- per-layer kernels ----------------
// hA, hB both fp16 (each 3.2MB -> L2-resident gather/sequential targets)
__global__ void node_k(const float* __restrict__ h, const float* __restrict__ ws, int l,
                       _Float16* __restrict__ hA, _Float16* __restrict__ hB) {
    __shared__ float sA[1024], sB[1024];
    const float* W1A = ws + W1A_OFF + l * 1024;
    const float* W1B = ws + W1B_OFF + l * 1024;
    for (int i = threadIdx.x; i < 1024; i += blockDim.x) { sA[i] = W1A[i]; sB[i] = W1B[i]; }
    __syncthreads();
    int t = blockIdx.x * blockDim.x + threadIdx.x;
    if (t >= NODE_F) return;
    int j = t & 31;
    float hv = h[t];
    float a = ws[C1_OFF + l * 32 + j];
    float b = 0.f;
#pragma unroll
    for (int k = 0; k < 32; ++k) {
        float hk = __shfl(hv, k, 32);
        a += hk * sA[k * 32 + j];
        b += hk * sB[k * 32 + j];
    }
    hA[t] = (_Float16)a;
    hB[t] = (_Float16)b;
}

// One wave handles NPW nodes as pairs (rolled loop): frag0 = 16 edges of n0, frag1 = n1.
// fp16 A/B frags -> mfma_f32_16x16x32_f16. C2 folded into MFMA C-operand.
// Software pipeline: csr packed 2 chunks ahead, hB gather 1 chunk ahead (clamped, branchless).
// A frag: lane l = row l&15, k = 8*(l>>4)+i. C/D: col=lane&15, row=4*(lane>>4)+reg.
__launch_bounds__(256, 5)
__global__ void edge_mfma_k(const int* __restrict__ offs, const int* __restrict__ csr,
                            const float* __restrict__ ws, int l,
                            const float* __restrict__ h, const _Float16* __restrict__ hA,
                            const _Float16* __restrict__ hB, float* __restrict__ hnext) {
    const int lane = threadIdx.x & 63;
    const int wid = (blockIdx.x * 256 + threadIdx.x) >> 6;
    const int r = lane & 15;   // A row (edge slot) / D col (channel)
    const int q = lane >> 4;   // channel octet / D row quad

    const _Float16* W2H = (const _Float16*)(ws + W2H_OFF);
    f16x8 b0, b1;
#pragma unroll
    for (int i = 0; i < 8; ++i) {
        b0[i] = W2H[l * 1024 + (8 * q + i) * 32 + r];
        b1[i] = W2H[l * 1024 + (8 * q + i) * 32 + 16 + r];
    }
    const float c2a = ws[C2_OFF + l * 32 + r];
    const float c2b = ws[C2_OFF + l * 32 + 16 + r];
    const f32x4 zc0 = {c2a, c2a, c2a, c2a};
    const f32x4 zc1 = {c2b, c2b, c2b, c2b};
    const f16x8 we = *(const f16x8*)((const _Float16*)(ws + WEH_OFF) + l * 32 + 8 * q);
    const f16x8 zero8 = {};

    const int nbase = wid * NPW;
#pragma unroll 1
    for (int ni = 0; ni < NPW; ni += 2) {
        const int n0 = nbase + ni;
        if (n0 >= N_NODES) return;
        const int n1 = n0 + 1;
        const bool has1 = (n1 < N_NODES);
        const int o0 = offs[n0];
        const int o1 = offs[n0 + 1];
        const int o2 = has1 ? offs[n1 + 1] : o1;

        const f16x8 hA0 = *(const f16x8*)(hA + n0 * 32 + 8 * q);
        const f16x8 hA1 = has1 ? *(const f16x8*)(hA + n1 * 32 + 8 * q) : zero8;

        float ns00 = 0.f, ns01 = 0.f, ns10 = 0.f, ns11 = 0.f;
        const int d0 = o1 - o0, d1 = o2 - o1;
        int nit = (d0 + 15) >> 4;
        int nit1 = (d1 + 15) >> 4;
        if (nit1 > nit) nit = nit1;

        if (nit > 0) {
            const int lim0 = (o1 - 1 > 0) ? o1 - 1 : 0;
            const int lim1 = (o2 - 1 > 0) ? o2 - 1 : 0;
#define CE0(EB) ({ int _e = (EB) + r; _e = (_e < lim0) ? _e : lim0; _e = (_e > 0) ? _e : 0; _e; })
#define CE1(EB) ({ int _e = (EB) + r; _e = (_e < lim1) ? _e : lim1; _e = (_e > 0) ? _e : 0; _e; })
            int eb0 = o0, eb1 = o1;
            int pc0 = csr[CE0(eb0)];
            int pc1 = csr[CE1(eb1)];
            f16x8 hc0 = *(const f16x8*)(hB + (pc0 & 0xFFFF) * 32 + 8 * q);
            f16x8 hc1 = *(const f16x8*)(hB + (pc1 & 0xFFFF) * 32 + 8 * q);
            int pn0 = csr[CE0(eb0 + 16)];
            int pn1 = csr[CE1(eb1 + 16)];
            for (int it = 0; it < nit; ++it) {
                // issue next-chunk gathers + next-next csr loads
                f16x8 hn0 = *(const f16x8*)(hB + (pn0 & 0xFFFF) * 32 + 8 * q);
                f16x8 hn1 = *(const f16x8*)(hB + (pn1 & 0xFFFF) * 32 + 8 * q);
                int pm0 = csr[CE0(eb0 + 32)];
                int pm1 = csr[CE1(eb1 + 32)];
                // compute current chunk
                _Float16 eah0 = h16((unsigned short)((unsigned)pc0 >> 16));
                _Float16 eah1 = h16((unsigned short)((unsigned)pc1 >> 16));
                f16x8 a0 = __builtin_elementwise_max(we * eah0 + (hA0 + hc0), zero8);
                f16x8 a1 = __builtin_elementwise_max(we * eah1 + (hA1 + hc1), zero8);
                f32x4 acc00 = __builtin_amdgcn_mfma_f32_16x16x32_f16(a0, b0, zc0, 0, 0, 0);
                f32x4 acc01 = __builtin_amdgcn_mfma_f32_16x16x32_f16(a0, b1, zc1, 0, 0, 0);
                f32x4 acc10 = __builtin_amdgcn_mfma_f32_16x16x32_f16(a1, b0, zc0, 0, 0, 0);
                f32x4 acc11 = __builtin_amdgcn_mfma_f32_16x16x32_f16(a1, b1, zc1, 0, 0, 0);
                int nr0 = o1 - eb0;
                int nr1 = o2 - eb1;
#pragma unroll
                for (int reg = 0; reg < 4; ++reg) {
                    int row = 4 * q + reg;
                    float m0 = (row < nr0) ? 1.f : 0.f;
                    float m1 = (row < nr1) ? 1.f : 0.f;
                    ns00 = fmaf(m0, fmaxf(acc00[reg], 0.f), ns00);
                    ns01 = fmaf(m0, fmaxf(acc01[reg], 0.f), ns01);
                    ns10 = fmaf(m1, fmaxf(acc10[reg], 0.f), ns10);
                    ns11 = fmaf(m1, fmaxf(acc11[reg], 0.f), ns11);
                }
                eb0 += 16; eb1 += 16;
                pc0 = pn0; pc1 = pn1;
                hc0 = hn0; hc1 = hn1;
                pn0 = pm0; pn1 = pm1;
            }
#undef CE0
#undef CE1
        }
        ns00 += __shfl_xor(ns00, 16, 64);
        ns00 += __shfl_xor(ns00, 32, 64);
        ns01 += __shfl_xor(ns01, 16, 64);
        ns01 += __shfl_xor(ns01, 32, 64);
        ns10 += __shfl_xor(ns10, 16, 64);
        ns10 += __shfl_xor(ns10, 32, 64);
        ns11 += __shfl_xor(ns11, 16, 64);
        ns11 += __shfl_xor(ns11, 32, 64);
        int ll = lane & 31;
        if (lane < 32) {
            float base = h[n0 * 32 + ll];
            hnext[n0 * 32 + ll] = base + ((ll & 16) ? ns01 : ns00);
        } else if (has1) {
            float base = h[n1 * 32 + ll];
            hnext[n1 * 32 + ll] = base + ((ll & 16) ? ns11 : ns10);
        }
    }
}

__global__ void head_k(const float* __restrict__ h, const int* __restrict__ cand,
                       const int* __restrict__ batch, const float* __restrict__ Wout,
                       const float* __restrict__ bout, float* __restrict__ out) {
    __shared__ float Lg[N_CAND];
    __shared__ int Sg[N_CAND];
    __shared__ float gm[N_GRAPHS], gs[N_GRAPHS];
    int t = threadIdx.x;  // 1024
    if (t < N_CAND) {
        int c = cand[t];
        float acc = bout[0];
#pragma unroll
        for (int j = 0; j < 32; ++j) acc += h[c * 32 + j] * Wout[j];
        Lg[t] = acc;
        Sg[t] = batch[c];
    }
    __syncthreads();
    if (t < 16 * N_GRAPHS) {
        int g = t >> 4, s = t & 15;
        float m = -1e30f;
        for (int i = s; i < N_CAND; i += 16)
            if (Sg[i] == g) m = fmaxf(m, Lg[i]);
#pragma unroll
        for (int d = 1; d < 16; d <<= 1) m = fmaxf(m, __shfl_xor(m, d, 64));
        float ssum = 0.f;
        for (int i = s; i < N_CAND; i += 16)
            if (Sg[i] == g) ssum += expf(Lg[i] - m);
#pragma unroll
        for (int d = 1; d < 16; d <<= 1) ssum += __shfl_xor(ssum, d, 64);
        if (s == 0) { gm[g] = m; gs[g] = logf(ssum); }
    }
    __syncthreads();
    if (t < N_CAND) out[t] = Lg[t] - gm[Sg[t]] - gs[Sg[t]];
}

extern "C" void kernel_launch(void* const* d_in, const int* in_sizes, int n_in,
                              void* d_out, int out_size, void* d_ws, size_t ws_size,
                              hipStream_t stream) {
    const float* x    = (const float*)d_in[0];
    const int*   ei   = (const int*)d_in[1];
    const float* eatt = (const float*)d_in[2];
    const int*   cand = (const int*)d_in[3];
    const int*   batch= (const int*)d_in[4];
    const float* Win  = (const float*)d_in[5];
    const float* bin  = (const float*)d_in[6];
    const float* W1   = (const float*)d_in[7];
    const float* b1   = (const float*)d_in[8];
    const float* g1   = (const float*)d_in[9];
    const float* be1  = (const float*)d_in[10];
    const float* m1   = (const float*)d_in[11];
    const float* v1   = (const float*)d_in[12];
    const float* W2   = (const float*)d_in[13];
    const float* b2   = (const float*)d_in[14];
    const float* g2   = (const float*)d_in[15];
    const float* be2  = (const float*)d_in[16];
    const float* m2   = (const float*)d_in[17];
    const float* v2   = (const float*)d_in[18];
    const float* Wout = (const float*)d_in[19];
    const float* bout = (const float*)d_in[20];
    float* out = (float*)d_out;
    float* ws = (float*)d_ws;

    float* h0 = ws + H_OFF;
    float* h1 = ws + H_OFF + NODE_F;
    _Float16* hA = (_Float16*)(ws + H_OFF + 2 * NODE_F);
    _Float16* hB = (_Float16*)(ws + H_OFF + 2 * NODE_F + NODE_F / 2);
    int* bh    = (int*)(ws + BH_OFF);
    int* boffs = (int*)(ws + BOFF_OFF);
    int* bcur  = (int*)(ws + BCUR_OFF);
    int* offs  = (int*)(ws + OFFS_OFF);
    int* csr   = (int*)(ws + CSR_OFF);
    int2* stage = (int2*)(ws + H_OFF + NODE_F);  // aliases h1+hA+hB (pre-node/edge only)

    prep_k<<<1, 256, 0, stream>>>(W1, b1, g1, be1, m1, v1, W2, b2, g2, be2, m2, v2, ws);

    zero_k<<<(NBK + 255) / 256, 256, 0, stream>>>(bh, NBK);
    bhist_k<<<NBLK_S, 512, 0, stream>>>(ei, bh);
    bscan_k<<<1, 1024, 0, stream>>>(bh, boffs, bcur);
    bscatter_k<<<NBLK_S, 512, 0, stream>>>(ei, eatt, bcur, stage);
    bsort2_k<<<NBK, 512, 0, stream>>>(boffs, stage, offs, csr);

    // embed + layer-0 node transform (after stage's aliased region is free)
    embed_node_k<<<(NODE_F + 1023) / 1024, 1024, 0, stream>>>(x, Win, bin, ws, h0, hA, hB);

    const int waves = (N_NODES + NPW - 1) / NPW;       // 6250
    const int eblocks = (waves + 3) / 4;               // 1563
    float* cur = h0;
    float* nxt = h1;
    for (int l = 0; l < L_LAYERS; ++l) {
        if (l > 0)
            node_k<<<(NODE_F + 1023) / 1024, 1024, 0, stream>>>(cur, ws, l, hA, hB);
        edge_mfma_k<<<eblocks, 256, 0, stream>>>(offs, csr, ws, l, cur, hA, hB, nxt);
        float* tmp = cur; cur = nxt; nxt = tmp;
    }

    head_k<<<1, 1024, 0, stream>>>(cur, cand, batch, Wout, bout, out);
}

// Round 12
// 281.480 us; speedup vs baseline: 1.5331x; 1.0691x over previous
//
#include <hip/hip_runtime.h>
#include <hip/hip_bf16.h>

#define N_NODES 50000
#define N_EDGES 1600000
#define N_CAND  1000
#define N_GRAPHS 50
#define EMB 32
#define L_LAYERS 4

#define BSH 8
#define BNODES 256
#define NBK ((N_NODES + BNODES - 1) >> BSH)    // 196 buckets of 256 nodes
#define STILE 2048
#define NBLK_S ((N_EDGES + STILE - 1) / STILE) // 782

#define NPW 8  // nodes per wave in edge kernel (4 pairs, rolled)

#define W1A_OFF 0
#define W1B_OFF 4096
#define W2_OFF  8192
#define WE_OFF  12288
#define C1_OFF  12416
#define C2_OFF  12544
#define W2H_OFF 12672   // f16[4][1024] = 2048 floats
#define WEH_OFF 14720   // f16[4][32]   = 64 floats
#define H_OFF   14848
#define NODE_F  (N_NODES * EMB)

// float-indexed: h0, h1 (fp32, NODE_F each), hA0/hB0 (f16, NODE_F floats total),
//                hA1/hB1 (f16, NODE_F floats total)
#define BH_OFF    (H_OFF + 4 * NODE_F)                   // int[NBK]
#define BOFF_OFF  (BH_OFF + NBK)                         // int[NBK+1]
#define BCUR_OFF  (BOFF_OFF + NBK + 1)                   // int[NBK]
#define OFFS_OFF  (BCUR_OFF + NBK)                       // int[N_NODES+1]
#define CSR_OFF   (OFFS_OFF + N_NODES + 1)               // int[N_EDGES] (src|f16ea<<16)
// stage (int2[N_EDGES] = 2*NODE_F floats) aliases [h1, hA0/hB0] (pre-embed only)

typedef float f32x4 __attribute__((ext_vector_type(4)));
typedef _Float16 f16x8 __attribute__((ext_vector_type(8)));

union HU { unsigned short u; _Float16 f; };
static __device__ __forceinline__ _Float16 h16(unsigned short u) { HU c; c.u = u; return c.f; }
static __device__ __forceinline__ unsigned short u16(_Float16 f) { HU c; c.f = f; return c.u; }

__global__ void prep_k(const float* __restrict__ W1, const float* __restrict__ b1,
                       const float* __restrict__ g1, const float* __restrict__ be1,
                       const float* __restrict__ m1, const float* __restrict__ v1,
                       const float* __restrict__ W2, const float* __restrict__ b2,
                       const float* __restrict__ g2, const float* __restrict__ be2,
                       const float* __restrict__ m2, const float* __restrict__ v2,
                       float* __restrict__ ws) {
    int t = threadIdx.x;  // 256 threads, 1 block
    _Float16* W2H = (_Float16*)(ws + W2H_OFF);
    _Float16* WEH = (_Float16*)(ws + WEH_OFF);
    for (int l = 0; l < L_LAYERS; ++l) {
        for (int i = t; i < 1024; i += 256) {
            int k = i >> 5, j = i & 31;
            float s1 = g1[l * 32 + j] * rsqrtf(v1[l * 32 + j] + 1e-5f);
            float s2 = g2[l * 32 + j] * rsqrtf(v2[l * 32 + j] + 1e-5f);
            ws[W1A_OFF + l * 1024 + i] = W1[(l * 65 + k) * 32 + j] * s1;
            ws[W1B_OFF + l * 1024 + i] = W1[(l * 65 + 32 + k) * 32 + j] * s1;
            float w2v = W2[(l * 32 + k) * 32 + j] * s2;
            ws[W2_OFF + l * 1024 + i] = w2v;
            W2H[l * 1024 + i] = (_Float16)w2v;
            if (k == 0) {
                float wev = W1[(l * 65 + 64) * 32 + j] * s1;
                ws[WE_OFF + l * 32 + j] = wev;
                WEH[l * 32 + j] = (_Float16)wev;
                ws[C1_OFF + l * 32 + j] = b1[l * 32 + j] * s1 + be1[l * 32 + j] - m1[l * 32 + j] * s1;
                ws[C2_OFF + l * 32 + j] = b2[l * 32 + j] * s2 + be2[l * 32 + j] - m2[l * 32 + j] * s2;
            }
        }
    }
}

// fused: h0 = x@Win+bin ; hA/hB for layer 0
__global__ void embed_node_k(const float* __restrict__ x, const float* __restrict__ Win,
                             const float* __restrict__ bin, const float* __restrict__ ws,
                             float* __restrict__ h, _Float16* __restrict__ hA,
                             _Float16* __restrict__ hB) {
    __shared__ float sA[1024], sB[1024];
    for (int i = threadIdx.x; i < 1024; i += blockDim.x) {
        sA[i] = ws[W1A_OFF + i];
        sB[i] = ws[W1B_OFF + i];
    }
    __syncthreads();
    int t = blockIdx.x * blockDim.x + threadIdx.x;
    if (t >= NODE_F) return;
    int n = t >> 5, j = t & 31;
    float hv = x[2 * n] * Win[j] + x[2 * n + 1] * Win[32 + j] + bin[j];
    h[t] = hv;
    float a = ws[C1_OFF + j];
    float b = 0.f;
#pragma unroll
    for (int k = 0; k < 32; ++k) {
        float hk = __shfl(hv, k, 32);
        a += hk * sA[k * 32 + j];
        b += hk * sB[k * 32 + j];
    }
    hA[t] = (_Float16)a;
    hB[t] = (_Float16)b;
}

__global__ void zero_k(int* __restrict__ p, int n) {
    int t = blockIdx.x * blockDim.x + threadIdx.x;
    if (t < n) p[t] = 0;
}

// per-block LDS histogram of dst>>BSH, one global atomic per bucket per block
__global__ void bhist_k(const int* __restrict__ ei, int* __restrict__ bh) {
    __shared__ int lh[NBK];
    for (int i = threadIdx.x; i < NBK; i += 512) lh[i] = 0;
    __syncthreads();
    int tb = blockIdx.x * STILE;
#pragma unroll
    for (int i = 0; i < STILE / 512; ++i) {
        int e = tb + i * 512 + threadIdx.x;
        if (e < N_EDGES) atomicAdd(&lh[ei[N_EDGES + e] >> BSH], 1);
    }
    __syncthreads();
    for (int i = threadIdx.x; i < NBK; i += 512)
        if (lh[i]) atomicAdd(&bh[i], lh[i]);
}

// single block: exclusive scan of bh[NBK] -> boffs, bcur
__global__ void bscan_k(const int* __restrict__ bh, int* __restrict__ boffs,
                        int* __restrict__ bcur) {
    __shared__ int part[1024];
    int t = threadIdx.x;
    int s = (t < NBK) ? bh[t] : 0;
    part[t] = s;
    __syncthreads();
    for (int d = 1; d < 1024; d <<= 1) {
        int v = (t >= d) ? part[t - d] : 0;
        __syncthreads();
        part[t] += v;
        __syncthreads();
    }
    if (t < NBK) {
        int run = part[t] - s;
        boffs[t] = run;
        bcur[t] = run;
    }
    if (t == 1023) boffs[NBK] = N_EDGES;
}

// block-aggregated binning: LDS hist -> one global reserve per bucket -> direct write
__global__ void bscatter_k(const int* __restrict__ ei, const float* __restrict__ ea,
                           int* __restrict__ bcur, int2* __restrict__ stage) {
    __shared__ int lofs[NBK];
    for (int i = threadIdx.x; i < NBK; i += 512) lofs[i] = 0;
    __syncthreads();
    int tb = blockIdx.x * STILE;
#pragma unroll
    for (int i = 0; i < STILE / 512; ++i) {
        int e = tb + i * 512 + threadIdx.x;
        if (e < N_EDGES) atomicAdd(&lofs[ei[N_EDGES + e] >> BSH], 1);
    }
    __syncthreads();
    for (int bk = threadIdx.x; bk < NBK; bk += 512) {
        int c = lofs[bk];
        lofs[bk] = c ? atomicAdd(&bcur[bk], c) : 0;
    }
    __syncthreads();
#pragma unroll
    for (int i = 0; i < STILE / 512; ++i) {
        int e = tb + i * 512 + threadIdx.x;
        if (e < N_EDGES) {
            int src = ei[e], dst = ei[N_EDGES + e];
            int bk = dst >> BSH;
            int pos = atomicAdd(&lofs[bk], 1);
            int2 p;
            p.x = src | ((dst & (BNODES - 1)) << 16);
            p.y = __float_as_int(ea[e]);
            stage[pos] = p;
        }
    }
}

// one block per 256-node bucket: hist + wave-scan prefix -> offs[n]; exact scatter.
// csr entry packed as src(16b) | f16(ea)(16b).
__global__ void bsort2_k(const int* __restrict__ boffs, const int2* __restrict__ stage,
                         int* __restrict__ offs, int* __restrict__ csr) {
    __shared__ int cnt[BNODES];
    __shared__ int pre[BNODES];
    __shared__ int cur[BNODES];
    const int b = blockIdx.x;
    const int nbase = b << BSH;
    const int t = threadIdx.x;  // 512
    const int beg = boffs[b], end = boffs[b + 1];
    if (t < BNODES) cnt[t] = 0;
    __syncthreads();
    for (int i = beg + t; i < end; i += 512)
        atomicAdd(&cnt[(stage[i].x >> 16) & (BNODES - 1)], 1);
    __syncthreads();
    if (t < 64) {
        int b4 = t * 4;
        int c0 = cnt[b4], c1 = cnt[b4 + 1], c2 = cnt[b4 + 2], c3 = cnt[b4 + 3];
        int s = c0 + c1 + c2 + c3;
        int run = s;
#pragma unroll
        for (int d = 1; d < 64; d <<= 1) {
            int v = __shfl_up(run, d, 64);
            if (t >= d) run += v;
        }
        int ex = run - s;  // exclusive
        pre[b4] = ex; pre[b4 + 1] = ex + c0; pre[b4 + 2] = ex + c0 + c1; pre[b4 + 3] = ex + c0 + c1 + c2;
    }
    __syncthreads();
    if (t < BNODES) {
        cur[t] = pre[t];
        int n = nbase + t;
        if (n < N_NODES) offs[n] = beg + pre[t];
    }
    if (b == NBK - 1 && t == 0) offs[N_NODES] = N_EDGES;
    __syncthreads();
    for (int i = beg + t; i < end; i += 512) {
        int2 p = stage[i];
        int dloc = (p.x >> 16) & (BNODES - 1);
        int pos = beg + atomicAdd(&cur[dloc], 1);
        unsigned short eh = u16((_Float16)__int_as_float(p.y));
        csr[pos] = (p.x & 0xFFFF) | ((int)eh << 16);
    }
}

// ---------------- fused per-layer kernel ----------------
// One wave handles NPW nodes as pairs: frag0 = 16 edges of n0, frag1 = n1.
// fp16 A/B frags -> mfma_f32_16x16x32_f16, C2 folded into MFMA C-operand,
// csr/hB software pipeline. EPILOGUE: with h_next[n] complete in registers,
// compute next layer's hA/hB via 32-shfl matvec (node_k fused; needs hA/hB
// double buffering since layer-l gathers race with layer-l+1 writes).
__launch_bounds__(256, 4)
__global__ void edge_mfma_k(const int* __restrict__ offs, const int* __restrict__ csr,
                            const float* __restrict__ ws, int l,
                            const float* __restrict__ h, const _Float16* __restrict__ hA,
                            const _Float16* __restrict__ hB, float* __restrict__ hnext,
                            _Float16* __restrict__ hAout, _Float16* __restrict__ hBout,
                            int doNext) {
    __shared__ float sA[1024], sB[1024];
    const int lw = (l < L_LAYERS - 1) ? l + 1 : l;  // next layer weights (unused if !doNext)
    for (int i = threadIdx.x; i < 1024; i += 256) {
        sA[i] = ws[W1A_OFF + lw * 1024 + i];
        sB[i] = ws[W1B_OFF + lw * 1024 + i];
    }
    __syncthreads();

    const int lane = threadIdx.x & 63;
    const int wid = (blockIdx.x * 256 + threadIdx.x) >> 6;
    const int r = lane & 15;   // A row (edge slot) / D col (channel)
    const int q = lane >> 4;   // channel octet / D row quad
    const int ll = lane & 31;

    const _Float16* W2H = (const _Float16*)(ws + W2H_OFF);
    f16x8 b0, b1;
#pragma unroll
    for (int i = 0; i < 8; ++i) {
        b0[i] = W2H[l * 1024 + (8 * q + i) * 32 + r];
        b1[i] = W2H[l * 1024 + (8 * q + i) * 32 + 16 + r];
    }
    const float c2a = ws[C2_OFF + l * 32 + r];
    const float c2b = ws[C2_OFF + l * 32 + 16 + r];
    const float c1n = ws[C1_OFF + lw * 32 + ll];
    const f32x4 zc0 = {c2a, c2a, c2a, c2a};
    const f32x4 zc1 = {c2b, c2b, c2b, c2b};
    const f16x8 we = *(const f16x8*)((const _Float16*)(ws + WEH_OFF) + l * 32 + 8 * q);
    const f16x8 zero8 = {};

    const int nbase = wid * NPW;
#pragma unroll 1
    for (int ni = 0; ni < NPW; ni += 2) {
        const int n0 = nbase + ni;
        if (n0 >= N_NODES) return;
        const int n1 = n0 + 1;
        const bool has1 = (n1 < N_NODES);
        const int o0 = offs[n0];
        const int o1 = offs[n0 + 1];
        const int o2 = has1 ? offs[n1 + 1] : o1;

        const f16x8 hA0 = *(const f16x8*)(hA + n0 * 32 + 8 * q);
        const f16x8 hA1 = has1 ? *(const f16x8*)(hA + n1 * 32 + 8 * q) : zero8;

        float ns00 = 0.f, ns01 = 0.f, ns10 = 0.f, ns11 = 0.f;
        const int d0 = o1 - o0, d1 = o2 - o1;
        int nit = (d0 + 15) >> 4;
        int nit1 = (d1 + 15) >> 4;
        if (nit1 > nit) nit = nit1;

        if (nit > 0) {
            const int lim0 = (o1 - 1 > 0) ? o1 - 1 : 0;
            const int lim1 = (o2 - 1 > 0) ? o2 - 1 : 0;
#define CE0(EB) ({ int _e = (EB) + r; _e = (_e < lim0) ? _e : lim0; _e = (_e > 0) ? _e : 0; _e; })
#define CE1(EB) ({ int _e = (EB) + r; _e = (_e < lim1) ? _e : lim1; _e = (_e > 0) ? _e : 0; _e; })
            int eb0 = o0, eb1 = o1;
            int pc0 = csr[CE0(eb0)];
            int pc1 = csr[CE1(eb1)];
            f16x8 hc0 = *(const f16x8*)(hB + (pc0 & 0xFFFF) * 32 + 8 * q);
            f16x8 hc1 = *(const f16x8*)(hB + (pc1 & 0xFFFF) * 32 + 8 * q);
            int pn0 = csr[CE0(eb0 + 16)];
            int pn1 = csr[CE1(eb1 + 16)];
            for (int it = 0; it < nit; ++it) {
                f16x8 hn0 = *(const f16x8*)(hB + (pn0 & 0xFFFF) * 32 + 8 * q);
                f16x8 hn1 = *(const f16x8*)(hB + (pn1 & 0xFFFF) * 32 + 8 * q);
                int pm0 = csr[CE0(eb0 + 32)];
                int pm1 = csr[CE1(eb1 + 32)];
                _Float16 eah0 = h16((unsigned short)((unsigned)pc0 >> 16));
                _Float16 eah1 = h16((unsigned short)((unsigned)pc1 >> 16));
                f16x8 a0 = __builtin_elementwise_max(we * eah0 + (hA0 + hc0), zero8);
                f16x8 a1 = __builtin_elementwise_max(we * eah1 + (hA1 + hc1), zero8);
                f32x4 acc00 = __builtin_amdgcn_mfma_f32_16x16x32_f16(a0, b0, zc0, 0, 0, 0);
                f32x4 acc01 = __builtin_amdgcn_mfma_f32_16x16x32_f16(a0, b1, zc1, 0, 0, 0);
                f32x4 acc10 = __builtin_amdgcn_mfma_f32_16x16x32_f16(a1, b0, zc0, 0, 0, 0);
                f32x4 acc11 = __builtin_amdgcn_mfma_f32_16x16x32_f16(a1, b1, zc1, 0, 0, 0);
                int nr0 = o1 - eb0;
                int nr1 = o2 - eb1;
#pragma unroll
                for (int reg = 0; reg < 4; ++reg) {
                    int row = 4 * q + reg;
                    float m0 = (row < nr0) ? 1.f : 0.f;
                    float m1 = (row < nr1) ? 1.f : 0.f;
                    ns00 = fmaf(m0, fmaxf(acc00[reg], 0.f), ns00);
                    ns01 = fmaf(m0, fmaxf(acc01[reg], 0.f), ns01);
                    ns10 = fmaf(m1, fmaxf(acc10[reg], 0.f), ns10);
                    ns11 = fmaf(m1, fmaxf(acc11[reg], 0.f), ns11);
                }
                eb0 += 16; eb1 += 16;
                pc0 = pn0; pc1 = pn1;
                hc0 = hn0; hc1 = hn1;
                pn0 = pm0; pn1 = pm1;
            }
#undef CE0
#undef CE1
        }
        ns00 += __shfl_xor(ns00, 16, 64);
        ns00 += __shfl_xor(ns00, 32, 64);
        ns01 += __shfl_xor(ns01, 16, 64);
        ns01 += __shfl_xor(ns01, 32, 64);
        ns10 += __shfl_xor(ns10, 16, 64);
        ns10 += __shfl_xor(ns10, 32, 64);
        ns11 += __shfl_xor(ns11, 16, 64);
        ns11 += __shfl_xor(ns11, 32, 64);

        // h_next value for this lane's (node, channel)
        float v;
        if (lane < 32) {
            v = h[n0 * 32 + ll] + ((ll & 16) ? ns01 : ns00);
            hnext[n0 * 32 + ll] = v;
        } else if (has1) {
            v = h[n1 * 32 + ll] + ((ll & 16) ? ns11 : ns10);
            hnext[n1 * 32 + ll] = v;
        } else {
            v = 0.f;
        }
        // fused node transform for next layer (32-shfl matvec per half-wave)
        if (doNext) {
            float a = c1n, b = 0.f;
#pragma unroll
            for (int k = 0; k < 32; ++k) {
                float hk = __shfl(v, k, 32);
                a += hk * sA[k * 32 + ll];
                b += hk * sB[k * 32 + ll];
            }
            if (lane < 32) {
                hAout[n0 * 32 + ll] = (_Float16)a;
                hBout[n0 * 32 + ll] = (_Float16)b;
            } else if (has1) {
                hAout[n1 * 32 + ll] = (_Float16)a;
                hBout[n1 * 32 + ll] = (_Float16)b;
            }
        }
    }
}

__global__ void head_k(const float* __restrict__ h, const int* __restrict__ cand,
                       const int* __restrict__ batch, const float* __restrict__ Wout,
                       const float* __restrict__ bout, float* __restrict__ out) {
    __shared__ float Lg[N_CAND];
    __shared__ int Sg[N_CAND];
    __shared__ float gm[N_GRAPHS], gs[N_GRAPHS];
    int t = threadIdx.x;  // 1024
    if (t < N_CAND) {
        int c = cand[t];
        float acc = bout[0];
#pragma unroll
        for (int j = 0; j < 32; ++j) acc += h[c * 32 + j] * Wout[j];
        Lg[t] = acc;
        Sg[t] = batch[c];
    }
    __syncthreads();
    if (t < 16 * N_GRAPHS) {
        int g = t >> 4, s = t & 15;
        float m = -1e30f;
        for (int i = s; i < N_CAND; i += 16)
            if (Sg[i] == g) m = fmaxf(m, Lg[i]);
#pragma unroll
        for (int d = 1; d < 16; d <<= 1) m = fmaxf(m, __shfl_xor(m, d, 64));
        float ssum = 0.f;
        for (int i = s; i < N_CAND; i += 16)
            if (Sg[i] == g) ssum += expf(Lg[i] - m);
#pragma unroll
        for (int d = 1; d < 16; d <<= 1) ssum += __shfl_xor(ssum, d, 64);
        if (s == 0) { gm[g] = m; gs[g] = logf(ssum); }
    }
    __syncthreads();
    if (t < N_CAND) out[t] = Lg[t] - gm[Sg[t]] - gs[Sg[t]];
}

extern "C" void kernel_launch(void* const* d_in, const int* in_sizes, int n_in,
                              void* d_out, int out_size, void* d_ws, size_t ws_size,
                              hipStream_t stream) {
    const float* x    = (const float*)d_in[0];
    const int*   ei   = (const int*)d_in[1];
    const float* eatt = (const float*)d_in[2];
    const int*   cand = (const int*)d_in[3];
    const int*   batch= (const int*)d_in[4];
    const float* Win  = (const float*)d_in[5];
    const float* bin  = (const float*)d_in[6];
    const float* W1   = (const float*)d_in[7];
    const float* b1   = (const float*)d_in[8];
    const float* g1   = (const float*)d_in[9];
    const float* be1  = (const float*)d_in[10];
    const float* m1   = (const float*)d_in[11];
    const float* v1   = (const float*)d_in[12];
    const float* W2   = (const float*)d_in[13];
    const float* b2   = (const float*)d_in[14];
    const float* g2   = (const float*)d_in[15];
    const float* be2  = (const float*)d_in[16];
    const float* m2   = (const float*)d_in[17];
    const float* v2   = (const float*)d_in[18];
    const float* Wout = (const float*)d_in[19];
    const float* bout = (const float*)d_in[20];
    float* out = (float*)d_out;
    float* ws = (float*)d_ws;

    float* h0 = ws + H_OFF;
    float* h1 = ws + H_OFF + NODE_F;
    _Float16* hA0 = (_Float16*)(ws + H_OFF + 2 * NODE_F);
    _Float16* hB0 = (_Float16*)(ws + H_OFF + 2 * NODE_F + NODE_F / 2);
    _Float16* hA1 = (_Float16*)(ws + H_OFF + 3 * NODE_F);
    _Float16* hB1 = (_Float16*)(ws + H_OFF + 3 * NODE_F + NODE_F / 2);
    int* bh    = (int*)(ws + BH_OFF);
    int* boffs = (int*)(ws + BOFF_OFF);
    int* bcur  = (int*)(ws + BCUR_OFF);
    int* offs  = (int*)(ws + OFFS_OFF);
    int* csr   = (int*)(ws + CSR_OFF);
    int2* stage = (int2*)(ws + H_OFF + NODE_F);  // aliases h1+hA0/hB0 (pre-embed only)

    prep_k<<<1, 256, 0, stream>>>(W1, b1, g1, be1, m1, v1, W2, b2, g2, be2, m2, v2, ws);

    zero_k<<<(NBK + 255) / 256, 256, 0, stream>>>(bh, NBK);
    bhist_k<<<NBLK_S, 512, 0, stream>>>(ei, bh);
    bscan_k<<<1, 1024, 0, stream>>>(bh, boffs, bcur);
    bscatter_k<<<NBLK_S, 512, 0, stream>>>(ei, eatt, bcur, stage);
    bsort2_k<<<NBK, 512, 0, stream>>>(boffs, stage, offs, csr);

    // embed + layer-0 node transform (after stage's aliased region is consumed)
    embed_node_k<<<(NODE_F + 1023) / 1024, 1024, 0, stream>>>(x, Win, bin, ws, h0, hA0, hB0);

    const int waves = (N_NODES + NPW - 1) / NPW;       // 6250
    const int eblocks = (waves + 3) / 4;               // 1563
    float* cur = h0;
    float* nxt = h1;
    _Float16 *cA = hA0, *cB = hB0, *nA = hA1, *nB = hB1;
    for (int l = 0; l < L_LAYERS; ++l) {
        edge_mfma_k<<<eblocks, 256, 0, stream>>>(offs, csr, ws, l, cur, cA, cB,
                                                 nxt, nA, nB, l < L_LAYERS - 1);
        float* tf = cur; cur = nxt; nxt = tf;
        _Float16* t1 = cA; cA = nA; nA = t1;
        _Float16* t2 = cB; cB = nB; nB = t2;
    }

    head_k<<<1, 1024, 0, stream>>>(cur, cand, batch, Wout, bout, out);
}

// Round 13
// 253.527 us; speedup vs baseline: 1.7022x; 1.1103x over previous
//
#include <hip/hip_runtime.h>
#include <hip/hip_bf16.h>

#define N_NODES 50000
#define N_EDGES 1600000
#define N_CAND  1000
#define N_GRAPHS 50
#define EMB 32
#define L_LAYERS 4

#define BSH 8
#define BNODES 256
#define NBK ((N_NODES + BNODES - 1) >> BSH)    // 196 buckets of 256 nodes
#define STILE 2048
#define NBLK_S ((N_EDGES + STILE - 1) / STILE) // 782

#define NPW 8  // nodes per wave (4 pairs, rolled); 50000 = 6250 waves exactly

#define W1A_OFF 0
#define W1B_OFF 4096
#define W2_OFF  8192
#define WE_OFF  12288
#define C1_OFF  12416
#define C2_OFF  12544
#define W2H_OFF  12672   // f16[4][1024] = 2048 floats
#define WEH_OFF  14720   // f16[4][32]   = 64 floats
#define W1AH_OFF 14784   // f16[4][1024] = 2048 floats
#define W1BH_OFF 16832   // f16[4][1024] = 2048 floats
#define H_OFF    18880
#define NODE_F  (N_NODES * EMB)

// float-indexed: h0, h1 (fp32, NODE_F each), hA0/hB0 (f16, NODE_F floats),
//                hA1/hB1 (f16, NODE_F floats)
#define BH_OFF    (H_OFF + 4 * NODE_F)                   // int[NBK]
#define BOFF_OFF  (BH_OFF + NBK)                         // int[NBK+1]
#define OFFS_OFF  (BOFF_OFF + NBK + 1)                   // int[N_NODES+1]
#define CSR_OFF   (OFFS_OFF + N_NODES + 1)               // int[N_EDGES] (src|f16ea<<16)
#define T_OFF     (CSR_OFF + N_EDGES)                    // int[NBK*NBLK_S] per-block hist/cursor
// stage (int2[N_EDGES] = 2*NODE_F floats) aliases [h1, hA0/hB0] (pre-embed only)

typedef float f32x4 __attribute__((ext_vector_type(4)));
typedef _Float16 f16x8 __attribute__((ext_vector_type(8)));

union HU { unsigned short u; _Float16 f; };
static __device__ __forceinline__ _Float16 h16(unsigned short u) { HU c; c.u = u; return c.f; }
static __device__ __forceinline__ unsigned short u16(_Float16 f) { HU c; c.f = f; return c.u; }

__global__ void prep_k(const float* __restrict__ W1, const float* __restrict__ b1,
                       const float* __restrict__ g1, const float* __restrict__ be1,
                       const float* __restrict__ m1, const float* __restrict__ v1,
                       const float* __restrict__ W2, const float* __restrict__ b2,
                       const float* __restrict__ g2, const float* __restrict__ be2,
                       const float* __restrict__ m2, const float* __restrict__ v2,
                       float* __restrict__ ws) {
    int t = threadIdx.x;  // 256 threads, 1 block
    _Float16* W2H  = (_Float16*)(ws + W2H_OFF);
    _Float16* WEH  = (_Float16*)(ws + WEH_OFF);
    _Float16* W1AH = (_Float16*)(ws + W1AH_OFF);
    _Float16* W1BH = (_Float16*)(ws + W1BH_OFF);
    for (int l = 0; l < L_LAYERS; ++l) {
        for (int i = t; i < 1024; i += 256) {
            int k = i >> 5, j = i & 31;
            float s1 = g1[l * 32 + j] * rsqrtf(v1[l * 32 + j] + 1e-5f);
            float s2 = g2[l * 32 + j] * rsqrtf(v2[l * 32 + j] + 1e-5f);
            float wa = W1[(l * 65 + k) * 32 + j] * s1;
            float wb = W1[(l * 65 + 32 + k) * 32 + j] * s1;
            ws[W1A_OFF + l * 1024 + i] = wa;
            ws[W1B_OFF + l * 1024 + i] = wb;
            W1AH[l * 1024 + i] = (_Float16)wa;
            W1BH[l * 1024 + i] = (_Float16)wb;
            float w2v = W2[(l * 32 + k) * 32 + j] * s2;
            ws[W2_OFF + l * 1024 + i] = w2v;
            W2H[l * 1024 + i] = (_Float16)w2v;
            if (k == 0) {
                float wev = W1[(l * 65 + 64) * 32 + j] * s1;
                ws[WE_OFF + l * 32 + j] = wev;
                WEH[l * 32 + j] = (_Float16)wev;
                ws[C1_OFF + l * 32 + j] = b1[l * 32 + j] * s1 + be1[l * 32 + j] - m1[l * 32 + j] * s1;
                ws[C2_OFF + l * 32 + j] = b2[l * 32 + j] * s2 + be2[l * 32 + j] - m2[l * 32 + j] * s2;
            }
        }
    }
}

// fused: h0 = x@Win+bin ; hA/hB for layer 0 (fp32 matvec, f16 store)
__global__ void embed_node_k(const float* __restrict__ x, const float* __restrict__ Win,
                             const float* __restrict__ bin, const float* __restrict__ ws,
                             float* __restrict__ h, _Float16* __restrict__ hA,
                             _Float16* __restrict__ hB) {
    __shared__ float sA[1024], sB[1024];
    for (int i = threadIdx.x; i < 1024; i += blockDim.x) {
        sA[i] = ws[W1A_OFF + i];
        sB[i] = ws[W1B_OFF + i];
    }
    __syncthreads();
    int t = blockIdx.x * blockDim.x + threadIdx.x;
    if (t >= NODE_F) return;
    int n = t >> 5, j = t & 31;
    float hv = x[2 * n] * Win[j] + x[2 * n + 1] * Win[32 + j] + bin[j];
    h[t] = hv;
    float a = ws[C1_OFF + j];
    float b = 0.f;
#pragma unroll
    for (int k = 0; k < 32; ++k) {
        float hk = __shfl(hv, k, 32);
        a += hk * sA[k * 32 + j];
        b += hk * sB[k * 32 + j];
    }
    hA[t] = (_Float16)a;
    hB[t] = (_Float16)b;
}

__global__ void zero_k(int* __restrict__ p, int n) {
    int t = blockIdx.x * blockDim.x + threadIdx.x;
    if (t < n) p[t] = 0;
}

// per-block LDS histogram of dst>>BSH; writes per-block counts to T[k][b] and global hist
__global__ void bhist_k(const int* __restrict__ ei, int* __restrict__ bh, int* __restrict__ T) {
    __shared__ int lh[NBK];
    for (int i = threadIdx.x; i < NBK; i += 512) lh[i] = 0;
    __syncthreads();
    int tb = blockIdx.x * STILE;
#pragma unroll
    for (int i = 0; i < STILE / 512; ++i) {
        int e = tb + i * 512 + threadIdx.x;
        if (e < N_EDGES) atomicAdd(&lh[ei[N_EDGES + e] >> BSH], 1);
    }
    __syncthreads();
    for (int i = threadIdx.x; i < NBK; i += 512) {
        int c = lh[i];
        T[i * NBLK_S + blockIdx.x] = c;
        if (c) atomicAdd(&bh[i], c);
    }
}

// single block: exclusive scan of bh[NBK] -> boffs
__global__ void bscan_k(const int* __restrict__ bh, int* __restrict__ boffs) {
    __shared__ int part[1024];
    int t = threadIdx.x;
    int s = (t < NBK) ? bh[t] : 0;
    part[t] = s;
    __syncthreads();
    for (int d = 1; d < 1024; d <<= 1) {
        int v = (t >= d) ? part[t - d] : 0;
        __syncthreads();
        part[t] += v;
        __syncthreads();
    }
    if (t < NBK) boffs[t] = part[t] - s;
    if (t == 1023) boffs[NBK] = N_EDGES;
}

// one block per bucket: exclusive scan of T[k][*] along blocks -> absolute base cursors
__global__ void bcursor_k(const int* __restrict__ boffs, int* __restrict__ T) {
    __shared__ int part[1024];
    int k = blockIdx.x, t = threadIdx.x;
    int v = (t < NBLK_S) ? T[k * NBLK_S + t] : 0;
    part[t] = v;
    __syncthreads();
    for (int d = 1; d < 1024; d <<= 1) {
        int u = (t >= d) ? part[t - d] : 0;
        __syncthreads();
        part[t] += u;
        __syncthreads();
    }
    if (t < NBLK_S) T[k * NBLK_S + t] = boffs[k] + part[t] - v;
}

// binning with precomputed per-block cursors: one read pass, LDS cursor alloc, direct write
__global__ void bscatter_k(const int* __restrict__ ei, const float* __restrict__ ea,
                           const int* __restrict__ T, int2* __restrict__ stage) {
    __shared__ int lofs[NBK];
    for (int i = threadIdx.x; i < NBK; i += 512)
        lofs[i] = T[i * NBLK_S + blockIdx.x];
    __syncthreads();
    int tb = blockIdx.x * STILE;
#pragma unroll
    for (int i = 0; i < STILE / 512; ++i) {
        int e = tb + i * 512 + threadIdx.x;
        if (e < N_EDGES) {
            int src = ei[e], dst = ei[N_EDGES + e];
            int bk = dst >> BSH;
            int pos = atomicAdd(&lofs[bk], 1);
            int2 p;
            p.x = src | ((dst & (BNODES - 1)) << 16);
            p.y = __float_as_int(ea[e]);
            stage[pos] = p;
        }
    }
}

// one block per 256-node bucket: hist + wave-scan prefix -> offs[n]; exact scatter.
// csr entry packed as src(16b) | f16(ea)(16b).
__global__ void bsort2_k(const int* __restrict__ boffs, const int2* __restrict__ stage,
                         int* __restrict__ offs, int* __restrict__ csr) {
    __shared__ int cnt[BNODES];
    __shared__ int pre[BNODES];
    __shared__ int cur[BNODES];
    const int b = blockIdx.x;
    const int nbase = b << BSH;
    const int t = threadIdx.x;  // 512
    const int beg = boffs[b], end = boffs[b + 1];
    if (t < BNODES) cnt[t] = 0;
    __syncthreads();
    for (int i = beg + t; i < end; i += 512)
        atomicAdd(&cnt[(stage[i].x >> 16) & (BNODES - 1)], 1);
    __syncthreads();
    if (t < 64) {
        int b4 = t * 4;
        int c0 = cnt[b4], c1 = cnt[b4 + 1], c2 = cnt[b4 + 2], c3 = cnt[b4 + 3];
        int s = c0 + c1 + c2 + c3;
        int run = s;
#pragma unroll
        for (int d = 1; d < 64; d <<= 1) {
            int v = __shfl_up(run, d, 64);
            if (t >= d) run += v;
        }
        int ex = run - s;  // exclusive
        pre[b4] = ex; pre[b4 + 1] = ex + c0; pre[b4 + 2] = ex + c0 + c1; pre[b4 + 3] = ex + c0 + c1 + c2;
    }
    __syncthreads();
    if (t < BNODES) {
        cur[t] = pre[t];
        int n = nbase + t;
        if (n < N_NODES) offs[n] = beg + pre[t];
    }
    if (b == NBK - 1 && t == 0) offs[N_NODES] = N_EDGES;
    __syncthreads();
    for (int i = beg + t; i < end; i += 512) {
        int2 p = stage[i];
        int dloc = (p.x >> 16) & (BNODES - 1);
        int pos = beg + atomicAdd(&cur[dloc], 1);
        unsigned short eh = u16((_Float16)__int_as_float(p.y));
        csr[pos] = (p.x & 0xFFFF) | ((int)eh << 16);
    }
}

// ---------------- fused per-layer kernel ----------------
// One wave handles NPW=8 nodes as 4 pairs. fp16 A/B frags -> mfma_f32_16x16x32_f16,
// C2 folded into MFMA C-operand, csr/hB software pipeline. Per-pair h_next rows are
// written to a wave-private XOR-swizzled LDS tile; the epilogue then computes the next
// layer's hA/hB with 4 MFMAs against f16 W1A/W1B (C1 folded) — no per-pair shfl matvec,
// no block barrier. (50000 = 6250*NPW exactly -> every in-range wave is full.)
__launch_bounds__(256, 4)
__global__ void edge_mfma_k(const int* __restrict__ offs, const int* __restrict__ csr,
                            const float* __restrict__ ws, int l,
                            const float* __restrict__ h, const _Float16* __restrict__ hA,
                            const _Float16* __restrict__ hB, float* __restrict__ hnext,
                            _Float16* __restrict__ hAout, _Float16* __restrict__ hBout,
                            int doNext) {
    __shared__ float vbuf[4 * 256];   // per-wave [8 nodes][32 ch], XOR-swizzled
    const int lane = threadIdx.x & 63;
    const int wid = (blockIdx.x * 256 + threadIdx.x) >> 6;
    const int r = lane & 15;   // A row (edge slot) / D col (channel)
    const int q = lane >> 4;   // channel octet / D row quad
    const int ll = lane & 31;
    float* vb = vbuf + (threadIdx.x >> 6) * 256;

    const _Float16* W2H = (const _Float16*)(ws + W2H_OFF);
    f16x8 b0, b1;
#pragma unroll
    for (int i = 0; i < 8; ++i) {
        b0[i] = W2H[l * 1024 + (8 * q + i) * 32 + r];
        b1[i] = W2H[l * 1024 + (8 * q + i) * 32 + 16 + r];
    }
    const float c2a = ws[C2_OFF + l * 32 + r];
    const float c2b = ws[C2_OFF + l * 32 + 16 + r];
    const f32x4 zc0 = {c2a, c2a, c2a, c2a};
    const f32x4 zc1 = {c2b, c2b, c2b, c2b};
    const f16x8 we = *(const f16x8*)((const _Float16*)(ws + WEH_OFF) + l * 32 + 8 * q);
    const f16x8 zero8 = {};

    const int nbase = wid * NPW;
#pragma unroll 1
    for (int ni = 0; ni < NPW; ni += 2) {
        const int n0 = nbase + ni;
        if (n0 >= N_NODES) return;
        const int n1 = n0 + 1;
        const bool has1 = (n1 < N_NODES);
        const int o0 = offs[n0];
        const int o1 = offs[n0 + 1];
        const int o2 = has1 ? offs[n1 + 1] : o1;

        const f16x8 hA0 = *(const f16x8*)(hA + n0 * 32 + 8 * q);
        const f16x8 hA1 = has1 ? *(const f16x8*)(hA + n1 * 32 + 8 * q) : zero8;

        float ns00 = 0.f, ns01 = 0.f, ns10 = 0.f, ns11 = 0.f;
        const int d0 = o1 - o0, d1 = o2 - o1;
        int nit = (d0 + 15) >> 4;
        int nit1 = (d1 + 15) >> 4;
        if (nit1 > nit) nit = nit1;

        if (nit > 0) {
            const int lim0 = (o1 - 1 > 0) ? o1 - 1 : 0;
            const int lim1 = (o2 - 1 > 0) ? o2 - 1 : 0;
#define CE0(EB) ({ int _e = (EB) + r; _e = (_e < lim0) ? _e : lim0; _e = (_e > 0) ? _e : 0; _e; })
#define CE1(EB) ({ int _e = (EB) + r; _e = (_e < lim1) ? _e : lim1; _e = (_e > 0) ? _e : 0; _e; })
            int eb0 = o0, eb1 = o1;
            int pc0 = csr[CE0(eb0)];
            int pc1 = csr[CE1(eb1)];
            f16x8 hc0 = *(const f16x8*)(hB + (pc0 & 0xFFFF) * 32 + 8 * q);
            f16x8 hc1 = *(const f16x8*)(hB + (pc1 & 0xFFFF) * 32 + 8 * q);
            int pn0 = csr[CE0(eb0 + 16)];
            int pn1 = csr[CE1(eb1 + 16)];
            for (int it = 0; it < nit; ++it) {
                f16x8 hn0 = *(const f16x8*)(hB + (pn0 & 0xFFFF) * 32 + 8 * q);
                f16x8 hn1 = *(const f16x8*)(hB + (pn1 & 0xFFFF) * 32 + 8 * q);
                int pm0 = csr[CE0(eb0 + 32)];
                int pm1 = csr[CE1(eb1 + 32)];
                _Float16 eah0 = h16((unsigned short)((unsigned)pc0 >> 16));
                _Float16 eah1 = h16((unsigned short)((unsigned)pc1 >> 16));
                f16x8 a0 = __builtin_elementwise_max(we * eah0 + (hA0 + hc0), zero8);
                f16x8 a1 = __builtin_elementwise_max(we * eah1 + (hA1 + hc1), zero8);
                f32x4 acc00 = __builtin_amdgcn_mfma_f32_16x16x32_f16(a0, b0, zc0, 0, 0, 0);
                f32x4 acc01 = __builtin_amdgcn_mfma_f32_16x16x32_f16(a0, b1, zc1, 0, 0, 0);
                f32x4 acc10 = __builtin_amdgcn_mfma_f32_16x16x32_f16(a1, b0, zc0, 0, 0, 0);
                f32x4 acc11 = __builtin_amdgcn_mfma_f32_16x16x32_f16(a1, b1, zc1, 0, 0, 0);
                int nr0 = o1 - eb0;
                int nr1 = o2 - eb1;
#pragma unroll
                for (int reg = 0; reg < 4; ++reg) {
                    int row = 4 * q + reg;
                    float m0 = (row < nr0) ? 1.f : 0.f;
                    float m1 = (row < nr1) ? 1.f : 0.f;
                    ns00 = fmaf(m0, fmaxf(acc00[reg], 0.f), ns00);
                    ns01 = fmaf(m0, fmaxf(acc01[reg], 0.f), ns01);
                    ns10 = fmaf(m1, fmaxf(acc10[reg], 0.f), ns10);
                    ns11 = fmaf(m1, fmaxf(acc11[reg], 0.f), ns11);
                }
                eb0 += 16; eb1 += 16;
                pc0 = pn0; pc1 = pn1;
                hc0 = hn0; hc1 = hn1;
                pn0 = pm0; pn1 = pm1;
            }
#undef CE0
#undef CE1
        }
        ns00 += __shfl_xor(ns00, 16, 64);
        ns00 += __shfl_xor(ns00, 32, 64);
        ns01 += __shfl_xor(ns01, 16, 64);
        ns01 += __shfl_xor(ns01, 32, 64);
        ns10 += __shfl_xor(ns10, 16, 64);
        ns10 += __shfl_xor(ns10, 32, 64);
        ns11 += __shfl_xor(ns11, 16, 64);
        ns11 += __shfl_xor(ns11, 32, 64);

        // h_next value for this lane's (node, channel); stash in swizzled LDS for epilogue
        float v;
        if (lane < 32) {
            v = h[n0 * 32 + ll] + ((ll & 16) ? ns01 : ns00);
            hnext[n0 * 32 + ll] = v;
        } else if (has1) {
            v = h[n1 * 32 + ll] + ((ll & 16) ? ns11 : ns10);
            hnext[n1 * 32 + ll] = v;
        } else {
            v = 0.f;
        }
        int node8 = ni + (lane >> 5);                 // 0..7
        vb[node8 * 32 + (ll ^ (node8 << 2))] = v;     // XOR swizzle, conflict-free write
    }

    // epilogue: next layer's hA/hB via 4 MFMAs (wave-private LDS, in-order DS, no barrier)
    if (doNext) {
        const int lw = l + 1;
        f16x8 av;
#pragma unroll
        for (int i = 0; i < 8; ++i) {
            int rr = r & 7;
            int ch = 8 * q + i;
            float vv = vb[rr * 32 + (ch ^ (rr << 2))];
            av[i] = (r < 8) ? (_Float16)vv : (_Float16)0.f;
        }
        const _Float16* W1AH = (const _Float16*)(ws + W1AH_OFF) + lw * 1024;
        const _Float16* W1BH = (const _Float16*)(ws + W1BH_OFF) + lw * 1024;
        f16x8 wa0, wa1, wb0, wb1;
#pragma unroll
        for (int i = 0; i < 8; ++i) {
            wa0[i] = W1AH[(8 * q + i) * 32 + r];
            wa1[i] = W1AH[(8 * q + i) * 32 + 16 + r];
            wb0[i] = W1BH[(8 * q + i) * 32 + r];
            wb1[i] = W1BH[(8 * q + i) * 32 + 16 + r];
        }
        const float c1a = ws[C1_OFF + lw * 32 + r];
        const float c1b = ws[C1_OFF + lw * 32 + 16 + r];
        const f32x4 ca = {c1a, c1a, c1a, c1a};
        const f32x4 cb = {c1b, c1b, c1b, c1b};
        const f32x4 z4 = {0.f, 0.f, 0.f, 0.f};
        f32x4 dA0 = __builtin_amdgcn_mfma_f32_16x16x32_f16(av, wa0, ca, 0, 0, 0);
        f32x4 dA1 = __builtin_amdgcn_mfma_f32_16x16x32_f16(av, wa1, cb, 0, 0, 0);
        f32x4 dB0 = __builtin_amdgcn_mfma_f32_16x16x32_f16(av, wb0, z4, 0, 0, 0);
        f32x4 dB1 = __builtin_amdgcn_mfma_f32_16x16x32_f16(av, wb1, z4, 0, 0, 0);
#pragma unroll
        for (int reg = 0; reg < 4; ++reg) {
            int row = 4 * q + reg;   // node index within wave (valid 0..7)
            int n = nbase + row;
            if (row < 8 && n < N_NODES) {
                hAout[n * 32 + r]      = (_Float16)dA0[reg];
                hAout[n * 32 + 16 + r] = (_Float16)dA1[reg];
                hBout[n * 32 + r]      = (_Float16)dB0[reg];
                hBout[n * 32 + 16 + r] = (_Float16)dB1[reg];
            }
        }
    }
}

__global__ void head_k(const float* __restrict__ h, const int* __restrict__ cand,
                       const int* __restrict__ batch, const float* __restrict__ Wout,
                       const float* __restrict__ bout, float* __restrict__ out) {
    __shared__ float Lg[N_CAND];
    __shared__ int Sg[N_CAND];
    __shared__ float gm[N_GRAPHS], gs[N_GRAPHS];
    int t = threadIdx.x;  // 1024
    if (t < N_CAND) {
        int c = cand[t];
        float acc = bout[0];
#pragma unroll
        for (int j = 0; j < 32; ++j) acc += h[c * 32 + j] * Wout[j];
        Lg[t] = acc;
        Sg[t] = batch[c];
    }
    __syncthreads();
    if (t < 16 * N_GRAPHS) {
        int g = t >> 4, s = t & 15;
        float m = -1e30f;
        for (int i = s; i < N_CAND; i += 16)
            if (Sg[i] == g) m = fmaxf(m, Lg[i]);
#pragma unroll
        for (int d = 1; d < 16; d <<= 1) m = fmaxf(m, __shfl_xor(m, d, 64));
        float ssum = 0.f;
        for (int i = s; i < N_CAND; i += 16)
            if (Sg[i] == g) ssum += expf(Lg[i] - m);
#pragma unroll
        for (int d = 1; d < 16; d <<= 1) ssum += __shfl_xor(ssum, d, 64);
        if (s == 0) { gm[g] = m; gs[g] = logf(ssum); }
    }
    __syncthreads();
    if (t < N_CAND) out[t] = Lg[t] - gm[Sg[t]] - gs[Sg[t]];
}

extern "C" void kernel_launch(void* const* d_in, const int* in_sizes, int n_in,
                              void* d_out, int out_size, void* d_ws, size_t ws_size,
                              hipStream_t stream) {
    const float* x    = (const float*)d_in[0];
    const int*   ei   = (const int*)d_in[1];
    const float* eatt = (const float*)d_in[2];
    const int*   cand = (const int*)d_in[3];
    const int*   batch= (const int*)d_in[4];
    const float* Win  = (const float*)d_in[5];
    const float* bin  = (const float*)d_in[6];
    const float* W1   = (const float*)d_in[7];
    const float* b1   = (const float*)d_in[8];
    const float* g1   = (const float*)d_in[9];
    const float* be1  = (const float*)d_in[10];
    const float* m1   = (const float*)d_in[11];
    const float* v1   = (const float*)d_in[12];
    const float* W2   = (const float*)d_in[13];
    const float* b2   = (const float*)d_in[14];
    const float* g2   = (const float*)d_in[15];
    const float* be2  = (const float*)d_in[16];
    const float* m2   = (const float*)d_in[17];
    const float* v2   = (const float*)d_in[18];
    const float* Wout = (const float*)d_in[19];
    const float* bout = (const float*)d_in[20];
    float* out = (float*)d_out;
    float* ws = (float*)d_ws;

    float* h0 = ws + H_OFF;
    float* h1 = ws + H_OFF + NODE_F;
    _Float16* hA0 = (_Float16*)(ws + H_OFF + 2 * NODE_F);
    _Float16* hB0 = (_Float16*)(ws + H_OFF + 2 * NODE_F + NODE_F / 2);
    _Float16* hA1 = (_Float16*)(ws + H_OFF + 3 * NODE_F);
    _Float16* hB1 = (_Float16*)(ws + H_OFF + 3 * NODE_F + NODE_F / 2);
    int* bh    = (int*)(ws + BH_OFF);
    int* boffs = (int*)(ws + BOFF_OFF);
    int* offs  = (int*)(ws + OFFS_OFF);
    int* csr   = (int*)(ws + CSR_OFF);
    int* T     = (int*)(ws + T_OFF);
    int2* stage = (int2*)(ws + H_OFF + NODE_F);  // aliases h1+hA0/hB0 (pre-embed only)

    prep_k<<<1, 256, 0, stream>>>(W1, b1, g1, be1, m1, v1, W2, b2, g2, be2, m2, v2, ws);

    zero_k<<<(NBK + 255) / 256, 256, 0, stream>>>(bh, NBK);
    bhist_k<<<NBLK_S, 512, 0, stream>>>(ei, bh, T);
    bscan_k<<<1, 1024, 0, stream>>>(bh, boffs);
    bcursor_k<<<NBK, 1024, 0, stream>>>(boffs, T);
    bscatter_k<<<NBLK_S, 512, 0, stream>>>(ei, eatt, T, stage);
    bsort2_k<<<NBK, 512, 0, stream>>>(boffs, stage, offs, csr);

    // embed + layer-0 node transform (after stage's aliased region is consumed)
    embed_node_k<<<(NODE_F + 1023) / 1024, 1024, 0, stream>>>(x, Win, bin, ws, h0, hA0, hB0);

    const int waves = (N_NODES + NPW - 1) / NPW;       // 6250
    const int eblocks = (waves + 3) / 4;               // 1563
    float* cur = h0;
    float* nxt = h1;
    _Float16 *cA = hA0, *cB = hB0, *nA = hA1, *nB = hB1;
    for (int l = 0; l < L_LAYERS; ++l) {
        edge_mfma_k<<<eblocks, 256, 0, stream>>>(offs, csr, ws, l, cur, cA, cB,
                                                 nxt, nA, nB, l < L_LAYERS - 1);
        float* tf = cur; cur = nxt; nxt = tf;
        _Float16* t1 = cA; cA = nA; nA = t1;
        _Float16* t2 = cB; cB = nB; nB = t2;
    }

    head_k<<<1, 1024, 0, stream>>>(cur, cand, batch, Wout, bout, out);
}

// Round 14
// 242.388 us; speedup vs baseline: 1.7804x; 1.0460x over previous
//
#include <hip/hip_runtime.h>
#include <hip/hip_bf16.h>

#define N_NODES 50000
#define N_EDGES 1600000
#define N_CAND  1000
#define N_GRAPHS 50
#define EMB 32
#define L_LAYERS 4

#define BSH 8
#define BNODES 256
#define NBK ((N_NODES + BNODES - 1) >> BSH)    // 196 buckets of 256 nodes
#define STILE 2048
#define NBLK_S ((N_EDGES + STILE - 1) / STILE) // 782

#define NPW 8  // nodes per wave (4 pairs); 50000 = 6250 waves exactly

#define W1A_OFF 0
#define W1B_OFF 4096
#define W2_OFF  8192
#define WE_OFF  12288
#define C1_OFF  12416
#define C2_OFF  12544
#define W2H_OFF  12672   // f16[4][1024] = 2048 floats
#define WEH_OFF  14720   // f16[4][32]   = 64 floats
#define W1AH_OFF 14784   // f16[4][1024] = 2048 floats
#define W1BH_OFF 16832   // f16[4][1024] = 2048 floats
#define H_OFF    18880
#define NODE_F  (N_NODES * EMB)

// float-indexed: h0, h1 (fp32, NODE_F each), hA0/hB0 (f16, NODE_F floats),
//                hA1/hB1 (f16, NODE_F floats)
#define BH_OFF    (H_OFF + 4 * NODE_F)                   // int[NBK]
#define BOFF_OFF  (BH_OFF + NBK)                         // int[NBK+1]
#define OFFS_OFF  (BOFF_OFF + NBK + 1)                   // int[N_NODES+1]
#define CSR_OFF   (OFFS_OFF + N_NODES + 1)               // int[N_EDGES] (src|f16ea<<16)
#define T_OFF     (CSR_OFF + N_EDGES)                    // int[NBK*NBLK_S]
// stage_e (int[N_EDGES] = 6.4MB) aliases h1; stage_d (byte[N_EDGES]) aliases hA0/hB0.

typedef float f32x4 __attribute__((ext_vector_type(4)));
typedef _Float16 f16x8 __attribute__((ext_vector_type(8)));

union HU { unsigned short u; _Float16 f; };
static __device__ __forceinline__ _Float16 h16(unsigned short u) { HU c; c.u = u; return c.f; }
static __device__ __forceinline__ unsigned short u16(_Float16 f) { HU c; c.f = f; return c.u; }

__global__ void prep_k(const float* __restrict__ W1, const float* __restrict__ b1,
                       const float* __restrict__ g1, const float* __restrict__ be1,
                       const float* __restrict__ m1, const float* __restrict__ v1,
                       const float* __restrict__ W2, const float* __restrict__ b2,
                       const float* __restrict__ g2, const float* __restrict__ be2,
                       const float* __restrict__ m2, const float* __restrict__ v2,
                       float* __restrict__ ws) {
    int t = threadIdx.x;  // 256 threads, 1 block
    _Float16* W2H  = (_Float16*)(ws + W2H_OFF);
    _Float16* WEH  = (_Float16*)(ws + WEH_OFF);
    _Float16* W1AH = (_Float16*)(ws + W1AH_OFF);
    _Float16* W1BH = (_Float16*)(ws + W1BH_OFF);
    for (int l = 0; l < L_LAYERS; ++l) {
        for (int i = t; i < 1024; i += 256) {
            int k = i >> 5, j = i & 31;
            float s1 = g1[l * 32 + j] * rsqrtf(v1[l * 32 + j] + 1e-5f);
            float s2 = g2[l * 32 + j] * rsqrtf(v2[l * 32 + j] + 1e-5f);
            float wa = W1[(l * 65 + k) * 32 + j] * s1;
            float wb = W1[(l * 65 + 32 + k) * 32 + j] * s1;
            ws[W1A_OFF + l * 1024 + i] = wa;
            ws[W1B_OFF + l * 1024 + i] = wb;
            W1AH[l * 1024 + i] = (_Float16)wa;
            W1BH[l * 1024 + i] = (_Float16)wb;
            float w2v = W2[(l * 32 + k) * 32 + j] * s2;
            ws[W2_OFF + l * 1024 + i] = w2v;
            W2H[l * 1024 + i] = (_Float16)w2v;
            if (k == 0) {
                float wev = W1[(l * 65 + 64) * 32 + j] * s1;
                ws[WE_OFF + l * 32 + j] = wev;
                WEH[l * 32 + j] = (_Float16)wev;
                ws[C1_OFF + l * 32 + j] = b1[l * 32 + j] * s1 + be1[l * 32 + j] - m1[l * 32 + j] * s1;
                ws[C2_OFF + l * 32 + j] = b2[l * 32 + j] * s2 + be2[l * 32 + j] - m2[l * 32 + j] * s2;
            }
        }
    }
}

// fused: h0 = x@Win+bin ; hA/hB for layer 0 (fp32 matvec, f16 store)
__global__ void embed_node_k(const float* __restrict__ x, const float* __restrict__ Win,
                             const float* __restrict__ bin, const float* __restrict__ ws,
                             float* __restrict__ h, _Float16* __restrict__ hA,
                             _Float16* __restrict__ hB) {
    __shared__ float sA[1024], sB[1024];
    for (int i = threadIdx.x; i < 1024; i += blockDim.x) {
        sA[i] = ws[W1A_OFF + i];
        sB[i] = ws[W1B_OFF + i];
    }
    __syncthreads();
    int t = blockIdx.x * blockDim.x + threadIdx.x;
    if (t >= NODE_F) return;
    int n = t >> 5, j = t & 31;
    float hv = x[2 * n] * Win[j] + x[2 * n + 1] * Win[32 + j] + bin[j];
    h[t] = hv;
    float a = ws[C1_OFF + j];
    float b = 0.f;
#pragma unroll
    for (int k = 0; k < 32; ++k) {
        float hk = __shfl(hv, k, 32);
        a += hk * sA[k * 32 + j];
        b += hk * sB[k * 32 + j];
    }
    hA[t] = (_Float16)a;
    hB[t] = (_Float16)b;
}

__global__ void zero_k(int* __restrict__ p, int n) {
    int t = blockIdx.x * blockDim.x + threadIdx.x;
    if (t < n) p[t] = 0;
}

// per-block LDS histogram of dst>>BSH; writes per-block counts to T[k][b] and global hist
__global__ void bhist_k(const int* __restrict__ ei, int* __restrict__ bh, int* __restrict__ T) {
    __shared__ int lh[NBK];
    for (int i = threadIdx.x; i < NBK; i += 512) lh[i] = 0;
    __syncthreads();
    int tb = blockIdx.x * STILE;
#pragma unroll
    for (int i = 0; i < STILE / 512; ++i) {
        int e = tb + i * 512 + threadIdx.x;
        if (e < N_EDGES) atomicAdd(&lh[ei[N_EDGES + e] >> BSH], 1);
    }
    __syncthreads();
    for (int i = threadIdx.x; i < NBK; i += 512) {
        int c = lh[i];
        T[i * NBLK_S + blockIdx.x] = c;
        if (c) atomicAdd(&bh[i], c);
    }
}

// single block: exclusive scan of bh[NBK] -> boffs
__global__ void bscan_k(const int* __restrict__ bh, int* __restrict__ boffs) {
    __shared__ int part[1024];
    int t = threadIdx.x;
    int s = (t < NBK) ? bh[t] : 0;
    part[t] = s;
    __syncthreads();
    for (int d = 1; d < 1024; d <<= 1) {
        int v = (t >= d) ? part[t - d] : 0;
        __syncthreads();
        part[t] += v;
        __syncthreads();
    }
    if (t < NBK) boffs[t] = part[t] - s;
    if (t == 1023) boffs[NBK] = N_EDGES;
}

// one block per bucket: exclusive scan of T[k][*] along blocks -> absolute base cursors
__global__ void bcursor_k(const int* __restrict__ boffs, int* __restrict__ T) {
    __shared__ int part[1024];
    int k = blockIdx.x, t = threadIdx.x;
    int v = (t < NBLK_S) ? T[k * NBLK_S + t] : 0;
    part[t] = v;
    __syncthreads();
    for (int d = 1; d < 1024; d <<= 1) {
        int u = (t >= d) ? part[t - d] : 0;
        __syncthreads();
        part[t] += u;
        __syncthreads();
    }
    if (t < NBLK_S) T[k * NBLK_S + t] = boffs[k] + part[t] - v;
}

// binning with precomputed cursors; emits final csr payload (src|f16ea<<16) + dloc byte
__global__ void bscatter_k(const int* __restrict__ ei, const float* __restrict__ ea,
                           const int* __restrict__ T, int* __restrict__ stage_e,
                           unsigned char* __restrict__ stage_d) {
    __shared__ int lofs[NBK];
    for (int i = threadIdx.x; i < NBK; i += 512)
        lofs[i] = T[i * NBLK_S + blockIdx.x];
    __syncthreads();
    int tb = blockIdx.x * STILE;
#pragma unroll
    for (int i = 0; i < STILE / 512; ++i) {
        int e = tb + i * 512 + threadIdx.x;
        if (e < N_EDGES) {
            int src = ei[e], dst = ei[N_EDGES + e];
            int bk = dst >> BSH;
            int pos = atomicAdd(&lofs[bk], 1);
            unsigned short eh = u16((_Float16)ea[e]);
            stage_e[pos] = src | ((int)eh << 16);
            stage_d[pos] = (unsigned char)(dst & (BNODES - 1));
        }
    }
}

// one block per 256-node bucket: hist + wave-scan prefix -> offs[n]; exact permutation.
__global__ void bsort2_k(const int* __restrict__ boffs, const int* __restrict__ stage_e,
                         const unsigned char* __restrict__ stage_d,
                         int* __restrict__ offs, int* __restrict__ csr) {
    __shared__ int cnt[BNODES];
    __shared__ int pre[BNODES];
    __shared__ int cur[BNODES];
    const int b = blockIdx.x;
    const int nbase = b << BSH;
    const int t = threadIdx.x;  // 512
    const int beg = boffs[b], end = boffs[b + 1];
    if (t < BNODES) cnt[t] = 0;
    __syncthreads();
    for (int i = beg + t; i < end; i += 512)
        atomicAdd(&cnt[stage_d[i]], 1);
    __syncthreads();
    if (t < 64) {
        int b4 = t * 4;
        int c0 = cnt[b4], c1 = cnt[b4 + 1], c2 = cnt[b4 + 2], c3 = cnt[b4 + 3];
        int s = c0 + c1 + c2 + c3;
        int run = s;
#pragma unroll
        for (int d = 1; d < 64; d <<= 1) {
            int v = __shfl_up(run, d, 64);
            if (t >= d) run += v;
        }
        int ex = run - s;  // exclusive
        pre[b4] = ex; pre[b4 + 1] = ex + c0; pre[b4 + 2] = ex + c0 + c1; pre[b4 + 3] = ex + c0 + c1 + c2;
    }
    __syncthreads();
    if (t < BNODES) {
        cur[t] = pre[t];
        int n = nbase + t;
        if (n < N_NODES) offs[n] = beg + pre[t];
    }
    if (b == NBK - 1 && t == 0) offs[N_NODES] = N_EDGES;
    __syncthreads();
    for (int i = beg + t; i < end; i += 512) {
        int dloc = stage_d[i];
        int pos = beg + atomicAdd(&cur[dloc], 1);
        csr[pos] = stage_e[i];
    }
}

// ---------------- fused per-layer kernel ----------------
// One wave = 8 nodes (4 pairs). Cross-pair software pipeline: all offs scalar-loaded,
// all 8 chunk-0 csr loads + 8 hB gathers + 8 chunk-1 csr loads issued BEFORE pair-0
// computes (collapses 4 serial prologue chains into one). fp16 MFMA edge math with
// C2 in the C-operand; per-wave LDS stash + 4-MFMA epilogue produces next layer hA/hB.
__launch_bounds__(256, 4)
__global__ void edge_mfma_k(const int* __restrict__ offs, const int* __restrict__ csr,
                            const float* __restrict__ ws, int l,
                            const float* __restrict__ h, const _Float16* __restrict__ hA,
                            const _Float16* __restrict__ hB, float* __restrict__ hnext,
                            _Float16* __restrict__ hAout, _Float16* __restrict__ hBout,
                            int doNext) {
    __shared__ float vbuf[4 * 256];   // per-wave [8 nodes][32 ch], XOR-swizzled
    const int lane = threadIdx.x & 63;
    const int wid = (blockIdx.x * 256 + threadIdx.x) >> 6;
    const int r = lane & 15;   // A row (edge slot) / D col (channel)
    const int q = lane >> 4;   // channel octet / D row quad
    const int ll = lane & 31;
    float* vb = vbuf + (threadIdx.x >> 6) * 256;
    const int nbase = wid * NPW;
    if (nbase >= N_NODES) return;   // grid tail only (50000 % 8 == 0)

    // wave-uniform segment bounds -> SGPRs
    int o[NPW + 1];
#pragma unroll
    for (int i = 0; i <= NPW; ++i)
        o[i] = __builtin_amdgcn_readfirstlane(offs[nbase + i]);

    const _Float16* W2H = (const _Float16*)(ws + W2H_OFF);
    f16x8 b0, b1;
#pragma unroll
    for (int i = 0; i < 8; ++i) {
        b0[i] = W2H[l * 1024 + (8 * q + i) * 32 + r];
        b1[i] = W2H[l * 1024 + (8 * q + i) * 32 + 16 + r];
    }
    const float c2a = ws[C2_OFF + l * 32 + r];
    const float c2b = ws[C2_OFF + l * 32 + 16 + r];
    const f32x4 zc0 = {c2a, c2a, c2a, c2a};
    const f32x4 zc1 = {c2b, c2b, c2b, c2b};
    const f16x8 we = *(const f16x8*)((const _Float16*)(ws + WEH_OFF) + l * 32 + 8 * q);
    const f16x8 zero8 = {};

#define CEI(EB, LIM) ({ int _e = (EB) + r; _e = (_e < (LIM)) ? _e : (LIM); _e = (_e > 0) ? _e : 0; _e; })

    // prologue: issue chunk-0 csr, chunk-0 gathers, chunk-1 csr for ALL 4 pairs
    int lim[NPW];
#pragma unroll
    for (int s = 0; s < NPW; ++s) {
        int e1 = o[s + 1] - 1;
        lim[s] = (e1 > 0) ? e1 : 0;
    }
    int pc[NPW], pn[NPW];
#pragma unroll
    for (int s = 0; s < NPW; ++s) pc[s] = csr[CEI(o[s], lim[s])];
    f16x8 hc[NPW];
#pragma unroll
    for (int s = 0; s < NPW; ++s)
        hc[s] = *(const f16x8*)(hB + (pc[s] & 0xFFFF) * 32 + 8 * q);
#pragma unroll
    for (int s = 0; s < NPW; ++s) pn[s] = csr[CEI(o[s] + 16, lim[s])];

#pragma unroll
    for (int p = 0; p < 4; ++p) {
        const int s0 = 2 * p, s1 = 2 * p + 1;
        const int n0 = nbase + s0;
        const int n1 = n0 + 1;
        const int o0 = o[s0], o1 = o[s1], o2 = o[s1 + 1];

        const f16x8 hA0 = *(const f16x8*)(hA + n0 * 32 + 8 * q);
        const f16x8 hA1 = *(const f16x8*)(hA + n1 * 32 + 8 * q);

        float ns00 = 0.f, ns01 = 0.f, ns10 = 0.f, ns11 = 0.f;
        int nit = (o1 - o0 + 15) >> 4;
        int nit1 = (o2 - o1 + 15) >> 4;
        if (nit1 > nit) nit = nit1;

        if (nit > 0) {
            const int lim0 = lim[s0], lim1 = lim[s1];
            int eb0 = o0, eb1 = o1;
            int pc0 = pc[s0], pc1 = pc[s1];
            f16x8 hc0 = hc[s0], hc1 = hc[s1];
            int pn0 = pn[s0], pn1 = pn[s1];
            for (int it = 0; it < nit; ++it) {
                f16x8 hn0 = *(const f16x8*)(hB + (pn0 & 0xFFFF) * 32 + 8 * q);
                f16x8 hn1 = *(const f16x8*)(hB + (pn1 & 0xFFFF) * 32 + 8 * q);
                int pm0 = csr[CEI(eb0 + 32, lim0)];
                int pm1 = csr[CEI(eb1 + 32, lim1)];
                _Float16 eah0 = h16((unsigned short)((unsigned)pc0 >> 16));
                _Float16 eah1 = h16((unsigned short)((unsigned)pc1 >> 16));
                f16x8 a0 = __builtin_elementwise_max(we * eah0 + (hA0 + hc0), zero8);
                f16x8 a1 = __builtin_elementwise_max(we * eah1 + (hA1 + hc1), zero8);
                f32x4 acc00 = __builtin_amdgcn_mfma_f32_16x16x32_f16(a0, b0, zc0, 0, 0, 0);
                f32x4 acc01 = __builtin_amdgcn_mfma_f32_16x16x32_f16(a0, b1, zc1, 0, 0, 0);
                f32x4 acc10 = __builtin_amdgcn_mfma_f32_16x16x32_f16(a1, b0, zc0, 0, 0, 0);
                f32x4 acc11 = __builtin_amdgcn_mfma_f32_16x16x32_f16(a1, b1, zc1, 0, 0, 0);
                int nr0 = o1 - eb0;
                int nr1 = o2 - eb1;
#pragma unroll
                for (int reg = 0; reg < 4; ++reg) {
                    int row = 4 * q + reg;
                    float m0 = (row < nr0) ? 1.f : 0.f;
                    float m1 = (row < nr1) ? 1.f : 0.f;
                    ns00 = fmaf(m0, fmaxf(acc00[reg], 0.f), ns00);
                    ns01 = fmaf(m0, fmaxf(acc01[reg], 0.f), ns01);
                    ns10 = fmaf(m1, fmaxf(acc10[reg], 0.f), ns10);
                    ns11 = fmaf(m1, fmaxf(acc11[reg], 0.f), ns11);
                }
                eb0 += 16; eb1 += 16;
                pc0 = pn0; pc1 = pn1;
                hc0 = hn0; hc1 = hn1;
                pn0 = pm0; pn1 = pm1;
            }
        }
        ns00 += __shfl_xor(ns00, 16, 64);
        ns00 += __shfl_xor(ns00, 32, 64);
        ns01 += __shfl_xor(ns01, 16, 64);
        ns01 += __shfl_xor(ns01, 32, 64);
        ns10 += __shfl_xor(ns10, 16, 64);
        ns10 += __shfl_xor(ns10, 32, 64);
        ns11 += __shfl_xor(ns11, 16, 64);
        ns11 += __shfl_xor(ns11, 32, 64);

        float v;
        if (lane < 32) {
            v = h[n0 * 32 + ll] + ((ll & 16) ? ns01 : ns00);
            hnext[n0 * 32 + ll] = v;
        } else {
            v = h[n1 * 32 + ll] + ((ll & 16) ? ns11 : ns10);
            hnext[n1 * 32 + ll] = v;
        }
        int node8 = s0 + (lane >> 5);                 // 0..7
        vb[node8 * 32 + (ll ^ (node8 << 2))] = v;     // XOR swizzle, conflict-free
    }
#undef CEI

    // epilogue: next layer's hA/hB via 4 MFMAs (wave-private LDS, in-order DS, no barrier)
    if (doNext) {
        const int lw = l + 1;
        f16x8 av;
#pragma unroll
        for (int i = 0; i < 8; ++i) {
            int rr = r & 7;
            int ch = 8 * q + i;
            float vv = vb[rr * 32 + (ch ^ (rr << 2))];
            av[i] = (r < 8) ? (_Float16)vv : (_Float16)0.f;
        }
        const _Float16* W1AH = (const _Float16*)(ws + W1AH_OFF) + lw * 1024;
        const _Float16* W1BH = (const _Float16*)(ws + W1BH_OFF) + lw * 1024;
        f16x8 wa0, wa1, wb0, wb1;
#pragma unroll
        for (int i = 0; i < 8; ++i) {
            wa0[i] = W1AH[(8 * q + i) * 32 + r];
            wa1[i] = W1AH[(8 * q + i) * 32 + 16 + r];
            wb0[i] = W1BH[(8 * q + i) * 32 + r];
            wb1[i] = W1BH[(8 * q + i) * 32 + 16 + r];
        }
        const float c1a = ws[C1_OFF + lw * 32 + r];
        const float c1b = ws[C1_OFF + lw * 32 + 16 + r];
        const f32x4 ca = {c1a, c1a, c1a, c1a};
        const f32x4 cb = {c1b, c1b, c1b, c1b};
        const f32x4 z4 = {0.f, 0.f, 0.f, 0.f};
        f32x4 dA0 = __builtin_amdgcn_mfma_f32_16x16x32_f16(av, wa0, ca, 0, 0, 0);
        f32x4 dA1 = __builtin_amdgcn_mfma_f32_16x16x32_f16(av, wa1, cb, 0, 0, 0);
        f32x4 dB0 = __builtin_amdgcn_mfma_f32_16x16x32_f16(av, wb0, z4, 0, 0, 0);
        f32x4 dB1 = __builtin_amdgcn_mfma_f32_16x16x32_f16(av, wb1, z4, 0, 0, 0);
#pragma unroll
        for (int reg = 0; reg < 4; ++reg) {
            int row = 4 * q + reg;   // node index within wave (valid 0..7)
            int n = nbase + row;
            if (row < 8 && n < N_NODES) {
                hAout[n * 32 + r]      = (_Float16)dA0[reg];
                hAout[n * 32 + 16 + r] = (_Float16)dA1[reg];
                hBout[n * 32 + r]      = (_Float16)dB0[reg];
                hBout[n * 32 + 16 + r] = (_Float16)dB1[reg];
            }
        }
    }
}

__global__ void head_k(const float* __restrict__ h, const int* __restrict__ cand,
                       const int* __restrict__ batch, const float* __restrict__ Wout,
                       const float* __restrict__ bout, float* __restrict__ out) {
    __shared__ float Lg[N_CAND];
    __shared__ int Sg[N_CAND];
    __shared__ float gm[N_GRAPHS], gs[N_GRAPHS];
    int t = threadIdx.x;  // 1024
    if (t < N_CAND) {
        int c = cand[t];
        float acc = bout[0];
#pragma unroll
        for (int j = 0; j < 32; ++j) acc += h[c * 32 + j] * Wout[j];
        Lg[t] = acc;
        Sg[t] = batch[c];
    }
    __syncthreads();
    if (t < 16 * N_GRAPHS) {
        int g = t >> 4, s = t & 15;
        float m = -1e30f;
        for (int i = s; i < N_CAND; i += 16)
            if (Sg[i] == g) m = fmaxf(m, Lg[i]);
#pragma unroll
        for (int d = 1; d < 16; d <<= 1) m = fmaxf(m, __shfl_xor(m, d, 64));
        float ssum = 0.f;
        for (int i = s; i < N_CAND; i += 16)
            if (Sg[i] == g) ssum += expf(Lg[i] - m);
#pragma unroll
        for (int d = 1; d < 16; d <<= 1) ssum += __shfl_xor(ssum, d, 64);
        if (s == 0) { gm[g] = m; gs[g] = logf(ssum); }
    }
    __syncthreads();
    if (t < N_CAND) out[t] = Lg[t] - gm[Sg[t]] - gs[Sg[t]];
}

extern "C" void kernel_launch(void* const* d_in, const int* in_sizes, int n_in,
                              void* d_out, int out_size, void* d_ws, size_t ws_size,
                              hipStream_t stream) {
    const float* x    = (const float*)d_in[0];
    const int*   ei   = (const int*)d_in[1];
    const float* eatt = (const float*)d_in[2];
    const int*   cand = (const int*)d_in[3];
    const int*   batch= (const int*)d_in[4];
    const float* Win  = (const float*)d_in[5];
    const float* bin  = (const float*)d_in[6];
    const float* W1   = (const float*)d_in[7];
    const float* b1   = (const float*)d_in[8];
    const float* g1   = (const float*)d_in[9];
    const float* be1  = (const float*)d_in[10];
    const float* m1   = (const float*)d_in[11];
    const float* v1   = (const float*)d_in[12];
    const float* W2   = (const float*)d_in[13];
    const float* b2   = (const float*)d_in[14];
    const float* g2   = (const float*)d_in[15];
    const float* be2  = (const float*)d_in[16];
    const float* m2   = (const float*)d_in[17];
    const float* v2   = (const float*)d_in[18];
    const float* Wout = (const float*)d_in[19];
    const float* bout = (const float*)d_in[20];
    float* out = (float*)d_out;
    float* ws = (float*)d_ws;

    float* h0 = ws + H_OFF;
    float* h1 = ws + H_OFF + NODE_F;
    _Float16* hA0 = (_Float16*)(ws + H_OFF + 2 * NODE_F);
    _Float16* hB0 = (_Float16*)(ws + H_OFF + 2 * NODE_F + NODE_F / 2);
    _Float16* hA1 = (_Float16*)(ws + H_OFF + 3 * NODE_F);
    _Float16* hB1 = (_Float16*)(ws + H_OFF + 3 * NODE_F + NODE_F / 2);
    int* bh    = (int*)(ws + BH_OFF);
    int* boffs = (int*)(ws + BOFF_OFF);
    int* offs  = (int*)(ws + OFFS_OFF);
    int* csr   = (int*)(ws + CSR_OFF);
    int* T     = (int*)(ws + T_OFF);
    int* stage_e = (int*)(ws + H_OFF + NODE_F);                 // aliases h1 (pre-edge)
    unsigned char* stage_d = (unsigned char*)(ws + H_OFF + 2 * NODE_F);  // aliases hA0 (pre-embed)

    prep_k<<<1, 256, 0, stream>>>(W1, b1, g1, be1, m1, v1, W2, b2, g2, be2, m2, v2, ws);

    zero_k<<<(NBK + 255) / 256, 256, 0, stream>>>(bh, NBK);
    bhist_k<<<NBLK_S, 512, 0, stream>>>(ei, bh, T);
    bscan_k<<<1, 1024, 0, stream>>>(bh, boffs);
    bcursor_k<<<NBK, 1024, 0, stream>>>(boffs, T);
    bscatter_k<<<NBLK_S, 512, 0, stream>>>(ei, eatt, T, stage_e, stage_d);
    bsort2_k<<<NBK, 512, 0, stream>>>(boffs, stage_e, stage_d, offs, csr);

    // embed + layer-0 node transform (after stage arrays are consumed)
    embed_node_k<<<(NODE_F + 1023) / 1024, 1024, 0, stream>>>(x, Win, bin, ws, h0, hA0, hB0);

    const int waves = (N_NODES + NPW - 1) / NPW;       // 6250
    const int eblocks = (waves + 3) / 4;               // 1563
    float* cur = h0;
    float* nxt = h1;
    _Float16 *cA = hA0, *cB = hB0, *nA = hA1, *nB = hB1;
    for (int l = 0; l < L_LAYERS; ++l) {
        edge_mfma_k<<<eblocks, 256, 0, stream>>>(offs, csr, ws, l, cur, cA, cB,
                                                 nxt, nA, nB, l < L_LAYERS - 1);
        float* tf = cur; cur = nxt; nxt = tf;
        _Float16* t1 = cA; cA = nA; nA = t1;
        _Float16* t2 = cB; cB = nB; nB = t2;
    }

    head_k<<<1, 1024, 0, stream>>>(cur, cand, batch, Wout, bout, out);
}